// Round 13
// baseline (751.004 us; speedup 1.0000x reference)
//
#include <hip/hip_runtime.h>
#include <cfloat>

#define N_PTS 2048
#define BATCH 8
#define KNN_K 20
#define XC_CH 512

constexpr float BN_SCALE_F = 0.9999950000374997f; // 1/sqrt(1+1e-5)

typedef _Float16 h8 __attribute__((ext_vector_type(8)));
typedef _Float16 h4v __attribute__((ext_vector_type(4)));
typedef float f32x4 __attribute__((ext_vector_type(4)));

// ---------------------------------------------------------------- sqnorm (layer-1 only, C=3)
__global__ void sqnorm_kernel(const float* __restrict__ in, int stride, int C,
                              float* __restrict__ xx) {
  int i = blockIdx.x * blockDim.x + threadIdx.x;
  if (i >= BATCH * N_PTS) return;
  const float* row = in + (size_t)i * stride;
  float s = 0.f;
  for (int c = 0; c < C; ++c) { float v = row[c]; s += v * v; }
  xx[i] = s;
}

// ---------------------------------------------------------------- fp32->f16 convert (packed, W5 only)
__global__ void cvt_f16_kernel(const float* __restrict__ in,
                               _Float16* __restrict__ out, int n4) {
  int t = blockIdx.x * 256 + threadIdx.x;
  if (t >= n4) return;
  float4 v = ((const float4*)in)[t];
  h4v o;
  o.x = (_Float16)v.x; o.y = (_Float16)v.y;
  o.z = (_Float16)v.z; o.w = (_Float16)v.w;
  ((h4v*)out)[t] = o;
}

// ---------------------------------------------------------------- selection core (proven r6/r7)
// v[32] per lane holds element gidx = i*64+lane; cached local top-3; 20 rounds
// of u64-key butterfly (sortable-f32<<32 | ~gidx: value desc, index asc on tie).
__device__ __forceinline__ void topk_select(float (&v)[32], int lane,
                                            int* __restrict__ knn_out, int out_base) {
  float t1 = -FLT_MAX, t2 = -FLT_MAX, t3 = -FLT_MAX;
  int i1 = -1, i2 = -1, i3 = -1;
#pragma unroll
  for (int i = 0; i < 32; ++i) {
    float val = v[i];
    bool g1 = val > t1, g2 = val > t2, g3 = val > t3;
    t3 = g2 ? t2 : (g3 ? val : t3);
    i3 = g2 ? i2 : (g3 ? i : i3);
    t2 = g1 ? t1 : (g2 ? val : t2);
    i2 = g1 ? i1 : (g2 ? i : i2);
    t1 = g1 ? val : t1;
    i1 = g1 ? i : i1;
  }
  unsigned consumed = 0u;

#pragma clang loop unroll(disable)
  for (int sel = 0; sel < KNN_K; ++sel) {
    if (i1 < 0) {                       // refill (rare: lane's 3rd+ win)
      float a1 = -FLT_MAX, a2 = -FLT_MAX, a3 = -FLT_MAX;
      int j1 = -1, j2 = -1, j3 = -1;
#pragma unroll
      for (int i = 0; i < 32; ++i) {
        float val = ((consumed >> i) & 1u) ? -FLT_MAX : v[i];
        bool g1 = val > a1, g2 = val > a2, g3 = val > a3;
        a3 = g2 ? a2 : (g3 ? val : a3);
        j3 = g2 ? j2 : (g3 ? i : j3);
        a2 = g1 ? a1 : (g2 ? val : a2);
        j2 = g1 ? j1 : (g2 ? i : j2);
        a1 = g1 ? val : a1;
        j1 = g1 ? i : j1;
      }
      t1 = a1; i1 = j1; t2 = a2; i2 = j2; t3 = a3; i3 = j3;
    }
    unsigned bits = __float_as_uint(t1);
    unsigned enc = bits ^ ((unsigned)((int)bits >> 31) | 0x80000000u);
    unsigned long long key =
        ((unsigned long long)enc << 32) | (unsigned)~(i1 * 64 + lane);
#pragma unroll
    for (int off = 32; off > 0; off >>= 1) {
      unsigned long long ok = __shfl_xor(key, off);
      if (ok > key) key = ok;
    }
    int bi = (int)~(unsigned)key;
    if (lane == 0) knn_out[out_base + sel] = bi;
    if ((bi & 63) == lane) {            // this lane's t1 won: pop cache
      consumed |= 1u << i1;
      t1 = t2; i1 = i2;
      t2 = t3; i2 = i3;
      t3 = -FLT_MAX; i3 = -1;
    }
  }
}

// ---------------------------------------------------------------- layer-1 knn: on-the-fly C=3 (no D)
// r9-proven form: 4096 blocks, ONE row per wave (no rr loop). r10/r11 showed
// any multi-row loop gets software-pipelined (two live v[32], VGPR 44->104,
// occupancy halves, 69->87us). Keep the single-row structure.
__global__ __launch_bounds__(256)
void topk3_kernel(const float* __restrict__ X, const float* __restrict__ xx,
                  int* __restrict__ knn_out) {
  __shared__ __align__(16) float colX[2048][4];
  int bl = blockIdx.x;
  int b = bl >> 9, rg = bl & 511;
  int row0 = rg * 4;
  int tid = threadIdx.x, wave = tid >> 6, lane = tid & 63;
  const float* Xb = X + (size_t)b * N_PTS * 3;
  const float* xxb = xx + b * N_PTS;
  for (int c = tid; c < 2048; c += 256) {
    colX[c][0] = Xb[c * 3];
    colX[c][1] = Xb[c * 3 + 1];
    colX[c][2] = Xb[c * 3 + 2];
    colX[c][3] = xxb[c];
  }
  __syncthreads();
  int r = row0 + wave;
  float4 rc = *(const float4*)&colX[r][0];
  float v[32];
#pragma unroll
  for (int i = 0; i < 32; ++i) {
    float4 cc = *(const float4*)&colX[i * 64 + lane][0];
    v[i] = 2.f * (rc.x * cc.x + rc.y * cc.y + rc.z * cc.z) - rc.w - cc.w;
  }
  topk_select(v, lane, knn_out, (b * N_PTS + r) * KNN_K);
}

// ---------------------------------------------------------------- top-20 from materialized D (layers 2-4)
__global__ void topk_kernel(const float* __restrict__ D, int b0,
                            int* __restrict__ knn_out) {
  int row = blockIdx.x * 4 + (threadIdx.x >> 6);
  int lane = threadIdx.x & 63;
  const float* dr = D + (size_t)row * N_PTS;
  float v[32];
#pragma unroll
  for (int i = 0; i < 32; ++i) v[i] = dr[i * 64 + lane];
  topk_select(v, lane, knn_out, (b0 * N_PTS + row) * KNN_K);
}

// ---------------------------------------------------------------- MFMA distance GEMM (split f16)
template<int K>
__global__ __launch_bounds__(256, 2)
void dist_mfma_kernel(const _Float16* __restrict__ Xh,
                      const _Float16* __restrict__ Xl,
                      const float* __restrict__ xx, int b0,
                      float* __restrict__ D) {
  constexpr int ST = 72;   // LDS row stride in f16 (64 + 8 pad)
  __shared__ __align__(16) _Float16 sm[4 * 128 * ST];
  _Float16* Ah = sm;
  _Float16* Al = sm + 128 * ST;
  _Float16* Bh = sm + 2 * 128 * ST;
  _Float16* Bl = sm + 3 * 128 * ST;

  int blk = blockIdx.x;
  int b_local = blk >> 8;
  int mblk = (blk >> 4) & 15, nblk = blk & 15;
  int b = b0 + b_local;
  int row0 = mblk * 128, col0 = nblk * 128;
  int tid = threadIdx.x;
  int wave = tid >> 6, lane = tid & 63;
  int wr = wave >> 1, wc = wave & 1;
  int quad = lane >> 4, l16 = lane & 15;

  const _Float16* XhB = Xh + (size_t)b * N_PTS * K;
  const _Float16* XlB = Xl + (size_t)b * N_PTS * K;

  f32x4 acc[4][4] = {};

  for (int k0 = 0; k0 < K; k0 += 64) {
    __syncthreads();
#pragma unroll
    for (int i = 0; i < 4; ++i) {
      int idx4 = tid + i * 256;
      int r = idx4 >> 3, c8 = idx4 & 7;
      int ko = k0 + c8 * 8;
      *(float4*)&Ah[r * ST + c8 * 8] = *(const float4*)&XhB[(size_t)(row0 + r) * K + ko];
      *(float4*)&Al[r * ST + c8 * 8] = *(const float4*)&XlB[(size_t)(row0 + r) * K + ko];
      *(float4*)&Bh[r * ST + c8 * 8] = *(const float4*)&XhB[(size_t)(col0 + r) * K + ko];
      *(float4*)&Bl[r * ST + c8 * 8] = *(const float4*)&XlB[(size_t)(col0 + r) * K + ko];
    }
    __syncthreads();
#pragma unroll
    for (int ks = 0; ks < 2; ++ks) {
      h8 bh[4], bl[4];
#pragma unroll
      for (int nt = 0; nt < 4; ++nt) {
        int off = (wc * 64 + nt * 16 + l16) * ST + ks * 32 + quad * 8;
        bh[nt] = *(const h8*)&Bh[off];
        bl[nt] = *(const h8*)&Bl[off];
      }
#pragma unroll
      for (int mt = 0; mt < 4; ++mt) {
        int off = (wr * 64 + mt * 16 + l16) * ST + ks * 32 + quad * 8;
        h8 ah = *(const h8*)&Ah[off];
        h8 al = *(const h8*)&Al[off];
#pragma unroll
        for (int nt = 0; nt < 4; ++nt) {
          acc[mt][nt] = __builtin_amdgcn_mfma_f32_16x16x32_f16(ah, bh[nt], acc[mt][nt], 0, 0, 0);
          acc[mt][nt] = __builtin_amdgcn_mfma_f32_16x16x32_f16(ah, bl[nt], acc[mt][nt], 0, 0, 0);
          acc[mt][nt] = __builtin_amdgcn_mfma_f32_16x16x32_f16(al, bh[nt], acc[mt][nt], 0, 0, 0);
        }
      }
    }
  }

  // epilogue: LDS transpose -> coalesced float4 stores with xx correction
  __syncthreads();
  float* S = (float*)sm;               // 128 x 132
#pragma unroll
  for (int mt = 0; mt < 4; ++mt)
#pragma unroll
    for (int nt = 0; nt < 4; ++nt)
#pragma unroll
      for (int i = 0; i < 4; ++i) {
        int rm = wr * 64 + mt * 16 + quad * 4 + i;
        int cn = wc * 64 + nt * 16 + l16;
        S[rm * 132 + cn] = 2.f * acc[mt][nt][i];
      }
  __syncthreads();
  const float* xxb = xx + b * N_PTS;
  float* Db = D + (size_t)b_local * N_PTS * N_PTS;
#pragma unroll
  for (int j = 0; j < 16; ++j) {
    int flat = j * 256 + tid;          // float4 index 0..4095
    int r = flat >> 5, c4 = (flat & 31) * 4;
    float xr = xxb[row0 + r];
    float4 v = *(const float4*)&S[r * 132 + c4];
    float4 xc4 = *(const float4*)&xxb[col0 + c4];
    float4 o = {v.x - xr - xc4.x, v.y - xr - xc4.y,
                v.z - xr - xc4.z, v.w - xr - xc4.w};
    *(float4*)&Db[(size_t)(row0 + r) * N_PTS + col0 + c4] = o;
  }
}

// ---------------------------------------------------------------- MFMA uv GEMM (split f16)
template<int K>
__global__ __launch_bounds__(256, 2)
void uv_mfma_kernel(const _Float16* __restrict__ Xh,
                    const _Float16* __restrict__ Xl,
                    const _Float16* __restrict__ Wph,
                    const _Float16* __restrict__ Wpl,
                    float* __restrict__ out, int NCOLS) {
  constexpr int ST = 72;
  __shared__ __align__(16) _Float16 sm[4 * 128 * ST];
  _Float16* Ah = sm;
  _Float16* Al = sm + 128 * ST;
  _Float16* Bh = sm + 2 * 128 * ST;
  _Float16* Bl = sm + 3 * 128 * ST;

  int nblk = blockIdx.x >> 7, mblk = blockIdx.x & 127;
  int row0 = mblk * 128, col0 = nblk * 128;
  int tid = threadIdx.x;
  int wave = tid >> 6, lane = tid & 63;
  int wr = wave >> 1, wc = wave & 1;
  int quad = lane >> 4, l16 = lane & 15;

  f32x4 acc[4][4] = {};

  for (int k0 = 0; k0 < K; k0 += 64) {
    __syncthreads();
#pragma unroll
    for (int i = 0; i < 4; ++i) {
      int idx4 = tid + i * 256;
      int r = idx4 >> 3, c8 = idx4 & 7;
      int ko = k0 + c8 * 8;
      *(float4*)&Ah[r * ST + c8 * 8] = *(const float4*)&Xh[(size_t)(row0 + r) * K + ko];
      *(float4*)&Al[r * ST + c8 * 8] = *(const float4*)&Xl[(size_t)(row0 + r) * K + ko];
      *(float4*)&Bh[r * ST + c8 * 8] = *(const float4*)&Wph[(size_t)(col0 + r) * K + ko];
      *(float4*)&Bl[r * ST + c8 * 8] = *(const float4*)&Wpl[(size_t)(col0 + r) * K + ko];
    }
    __syncthreads();
#pragma unroll
    for (int ks = 0; ks < 2; ++ks) {
      h8 bh[4], bl[4];
#pragma unroll
      for (int nt = 0; nt < 4; ++nt) {
        int off = (wc * 64 + nt * 16 + l16) * ST + ks * 32 + quad * 8;
        bh[nt] = *(const h8*)&Bh[off];
        bl[nt] = *(const h8*)&Bl[off];
      }
#pragma unroll
      for (int mt = 0; mt < 4; ++mt) {
        int off = (wr * 64 + mt * 16 + l16) * ST + ks * 32 + quad * 8;
        h8 ah = *(const h8*)&Ah[off];
        h8 al = *(const h8*)&Al[off];
#pragma unroll
        for (int nt = 0; nt < 4; ++nt) {
          acc[mt][nt] = __builtin_amdgcn_mfma_f32_16x16x32_f16(ah, bh[nt], acc[mt][nt], 0, 0, 0);
          acc[mt][nt] = __builtin_amdgcn_mfma_f32_16x16x32_f16(ah, bl[nt], acc[mt][nt], 0, 0, 0);
          acc[mt][nt] = __builtin_amdgcn_mfma_f32_16x16x32_f16(al, bh[nt], acc[mt][nt], 0, 0, 0);
        }
      }
    }
  }

  __syncthreads();
  float* S = (float*)sm;
#pragma unroll
  for (int mt = 0; mt < 4; ++mt)
#pragma unroll
    for (int nt = 0; nt < 4; ++nt)
#pragma unroll
      for (int i = 0; i < 4; ++i) {
        int rm = wr * 64 + mt * 16 + quad * 4 + i;
        int cn = wc * 64 + nt * 16 + l16;
        S[rm * 132 + cn] = acc[mt][nt][i];
      }
  __syncthreads();
#pragma unroll
  for (int j = 0; j < 16; ++j) {
    int flat = j * 256 + tid;
    int r = flat >> 5, c4 = (flat & 31) * 4;
    float4 v = *(const float4*)&S[r * 132 + c4];
    *(float4*)&out[(size_t)(row0 + r) * NCOLS + col0 + c4] = v;
  }
}

// ---------------------------------------------------------------- MFMA W5 GEMM + bn/lrelu + pooling
__global__ __launch_bounds__(256, 2)
void w5_mfma_kernel(const _Float16* __restrict__ xch,
                    const _Float16* __restrict__ w5h,
                    const float* __restrict__ g5,
                    const float* __restrict__ b5,
                    float* __restrict__ pmax, float* __restrict__ psum) {
  constexpr int ST = 72;
  __shared__ __align__(16) _Float16 sm[2 * 128 * ST];
  __shared__ float redm[2][128], reds[2][128];
  _Float16* Ah = sm;
  _Float16* Bh = sm + 128 * ST;

  int mblk = blockIdx.x >> 3, nblk = blockIdx.x & 7;
  int row0 = mblk * 128, o0 = nblk * 128;
  int tid = threadIdx.x;
  int wave = tid >> 6, lane = tid & 63;
  int wr = wave >> 1, wc = wave & 1;
  int quad = lane >> 4, l16 = lane & 15;

  f32x4 acc[4][4] = {};

  for (int k0 = 0; k0 < XC_CH; k0 += 64) {
    __syncthreads();
#pragma unroll
    for (int i = 0; i < 4; ++i) {       // 1024 (r,c8) pairs
      int idx4 = tid + i * 256;
      int r = idx4 >> 3, c8 = idx4 & 7;
      int ko = k0 + c8 * 8;
      *(float4*)&Ah[r * ST + c8 * 8] = *(const float4*)&xch[(size_t)(row0 + r) * XC_CH + ko];
      *(float4*)&Bh[r * ST + c8 * 8] = *(const float4*)&w5h[(size_t)(o0 + r) * XC_CH + ko];
    }
    __syncthreads();
#pragma unroll
    for (int ks = 0; ks < 2; ++ks) {
      h8 bh[4];
#pragma unroll
      for (int nt = 0; nt < 4; ++nt)
        bh[nt] = *(const h8*)&Bh[(wc * 64 + nt * 16 + l16) * ST + ks * 32 + quad * 8];
#pragma unroll
      for (int mt = 0; mt < 4; ++mt) {
        h8 ah = *(const h8*)&Ah[(wr * 64 + mt * 16 + l16) * ST + ks * 32 + quad * 8];
#pragma unroll
        for (int nt = 0; nt < 4; ++nt)
          acc[mt][nt] = __builtin_amdgcn_mfma_f32_16x16x32_f16(ah, bh[nt], acc[mt][nt], 0, 0, 0);
      }
    }
  }

#pragma unroll
  for (int nt = 0; nt < 4; ++nt) {
    int gcol = o0 + wc * 64 + nt * 16 + l16;
    float g = g5[gcol], be = b5[gcol];
    float pm = -FLT_MAX, ps = 0.f;
#pragma unroll
    for (int mt = 0; mt < 4; ++mt)
#pragma unroll
      for (int i = 0; i < 4; ++i) {
        float y = g * (acc[mt][nt][i] * BN_SCALE_F) + be;
        y = (y > 0.f) ? y : 0.2f * y;
        pm = fmaxf(pm, y);
        ps += y;
      }
#pragma unroll
    for (int off = 16; off <= 32; off <<= 1) {
      pm = fmaxf(pm, __shfl_xor(pm, off));
      ps += __shfl_xor(ps, off);
    }
    if (quad == 0) {
      redm[wr][wc * 64 + nt * 16 + l16] = pm;
      reds[wr][wc * 64 + nt * 16 + l16] = ps;
    }
  }
  __syncthreads();
  if (tid < 128) {
    float m = fmaxf(redm[0][tid], redm[1][tid]);
    float s = reds[0][tid] + reds[1][tid];
    int bb = mblk >> 4, ch = mblk & 15;
    size_t off = (size_t)(bb * 16 + ch) * 1024 + o0 + tid;
    pmax[off] = m;
    psum[off] = s;
  }
}

// ---------------------------------------------------------------- W' prep (layer1, fp32)
__global__ void prep_wp3_kernel(const float* __restrict__ W,
                                float* __restrict__ Wp, int O, int C) {
  int t = blockIdx.x * 256 + threadIdx.x;
  if (t >= 2 * O * C) return;
  int o = t / C, c = t % C;
  Wp[t] = (o < O) ? W[(size_t)o * 2 * C + c]
                  : (W[(size_t)(o - O) * 2 * C + C + c] -
                     W[(size_t)(o - O) * 2 * C + c]);
}

// ---------------------------------------------------------------- W' prep (f16 hi/lo)
__global__ void prep_wpf16_kernel(const float* __restrict__ W,
                                  _Float16* __restrict__ Wph,
                                  _Float16* __restrict__ Wpl, int O, int C) {
  int t = blockIdx.x * 256 + threadIdx.x;
  if (t >= 2 * O * C) return;
  int o = t / C, c = t % C;
  float val = (o < O) ? W[(size_t)o * 2 * C + c]
                      : (W[(size_t)(o - O) * 2 * C + C + c] -
                         W[(size_t)(o - O) * 2 * C + c]);
  _Float16 hv = (_Float16)val;
  Wph[t] = hv;
  Wpl[t] = (_Float16)(val - (float)hv);
}

// ---------------------------------------------------------------- layer-1 uv (K=3, fp32)
__global__ void gemm_uv3_kernel(const float* __restrict__ x,
                                const float* __restrict__ Wp,
                                float* __restrict__ out) {
  int t = blockIdx.x * 256 + threadIdx.x;
  if (t >= BATCH * N_PTS * 128) return;
  int n = t >> 7, o = t & 127;
  const float* xr = x + (size_t)n * 3;
  const float* wr = Wp + (size_t)o * 3;
  out[t] = xr[0] * wr[0] + xr[1] * wr[1] + xr[2] * wr[2];
}

// ---------------------------------------------------------------- edge gather+max, fused next-layer prep
// Writes: xch slice (f16, stride XC_CH) always; if WS also the packed hi/lo
// split (Xh/Xl, stride O) and xx[n] = sum_o mx^2 (replaces split_sq_kernel).
template<int O, bool WS>
__global__ void edge_max_kernel(const float* __restrict__ uv,
                                const int* __restrict__ knn_idx,
                                const float* __restrict__ gamma,
                                const float* __restrict__ beta,
                                _Float16* __restrict__ xch_out,
                                _Float16* __restrict__ Xh,
                                _Float16* __restrict__ Xl,
                                float* __restrict__ xx) {
  constexpr int P = 256 / O;
  int tid = threadIdx.x;
  int p = tid / O, o = tid % O;
  int n = blockIdx.x * P + p;
  int b = n / N_PTS;
  float v = uv[(size_t)n * (2 * O) + O + o];
  float g = gamma[o], be = beta[o];
  const int* ir = knn_idx + (size_t)n * KNN_K;
  int mk[KNN_K];
#pragma unroll
  for (int k = 0; k < KNN_K; ++k) mk[k] = ir[k];
  float mx = -FLT_MAX;
#pragma unroll
  for (int k = 0; k < KNN_K; ++k) {
    float u = uv[(size_t)(b * N_PTS + mk[k]) * (2 * O) + o];
    float y = g * ((u + v) * BN_SCALE_F) + be;
    y = (y > 0.f) ? y : 0.2f * y;
    mx = fmaxf(mx, y);
  }
  xch_out[(size_t)n * XC_CH + o] = (_Float16)mx;
  if constexpr (WS) {
    _Float16 hv = (_Float16)mx;
    Xh[(size_t)n * O + o] = hv;
    Xl[(size_t)n * O + o] = (_Float16)(mx - (float)hv);
    float sq = mx * mx;
    if constexpr (O == 64) {
#pragma unroll
      for (int off = 32; off > 0; off >>= 1) sq += __shfl_xor(sq, off);
      if ((tid & 63) == 0) xx[n] = sq;
    } else {  // O == 128: two waves per row
      __shared__ float sred[4];
#pragma unroll
      for (int off = 32; off > 0; off >>= 1) sq += __shfl_xor(sq, off);
      if ((tid & 63) == 0) sred[tid >> 6] = sq;
      __syncthreads();
      if (tid < P) xx[blockIdx.x * P + tid] = sred[tid * 2] + sred[tid * 2 + 1];
    }
  }
}

// ---------------------------------------------------------------- head
__global__ void pool_kernel(const float* __restrict__ pmax,
                            const float* __restrict__ psum,
                            float* __restrict__ gvec) {
  int t = blockIdx.x * 256 + threadIdx.x;   // 8192 threads
  int b = t >> 10, o = t & 1023;
  float mx = -FLT_MAX, sm = 0.f;
#pragma unroll
  for (int ch = 0; ch < 16; ++ch) {
    size_t idx = (size_t)(b * 16 + ch) * 1024 + o;
    mx = fmaxf(mx, pmax[idx]);
    sm += psum[idx];
  }
  gvec[b * 2048 + o] = mx;
  gvec[b * 2048 + 1024 + o] = sm * (1.f / 2048.f);
}

__global__ void fc1_kernel(const float* __restrict__ gvec,
                           const float* __restrict__ L1,
                           const float* __restrict__ g6, const float* __restrict__ b6,
                           float* __restrict__ h1) {
  int o = blockIdx.x * 4 + (threadIdx.x >> 6);   // 0..511
  int lane = threadIdx.x & 63;
  float4 w[8];
#pragma unroll
  for (int i = 0; i < 8; ++i)
    w[i] = *(const float4*)&L1[(size_t)o * 2048 + i * 256 + lane * 4];
  float g = g6[o], be = b6[o];
  for (int b = 0; b < BATCH; ++b) {
    float s = 0.f;
#pragma unroll
    for (int i = 0; i < 8; ++i) {
      float4 v = *(const float4*)&gvec[b * 2048 + i * 256 + lane * 4];
      s += w[i].x * v.x + w[i].y * v.y + w[i].z * v.z + w[i].w * v.w;
    }
#pragma unroll
    for (int off = 32; off > 0; off >>= 1) s += __shfl_down(s, off);
    if (lane == 0) {
      float y = g * (s * BN_SCALE_F) + be;
      h1[b * 512 + o] = (y > 0.f) ? y : 0.2f * y;
    }
  }
}

__global__ void fc2_kernel(const float* __restrict__ h1,
                           const float* __restrict__ L2, const float* __restrict__ L2b,
                           const float* __restrict__ g7, const float* __restrict__ b7,
                           float* __restrict__ h2) {
  int w = blockIdx.x * 4 + (threadIdx.x >> 6);   // 0..2047
  int lane = threadIdx.x & 63;
  int b = w >> 8, o = w & 255;
  float s = 0.f;
#pragma unroll
  for (int i = 0; i < 2; ++i) {
    float4 wv = *(const float4*)&L2[(size_t)o * 512 + i * 256 + lane * 4];
    float4 hv = *(const float4*)&h1[b * 512 + i * 256 + lane * 4];
    s += wv.x * hv.x + wv.y * hv.y + wv.z * hv.z + wv.w * hv.w;
  }
#pragma unroll
  for (int off = 32; off > 0; off >>= 1) s += __shfl_down(s, off);
  if (lane == 0) {
    float y = g7[o] * ((s + L2b[o]) * BN_SCALE_F) + b7[o];
    h2[b * 256 + o] = (y > 0.f) ? y : 0.2f * y;
  }
}

__global__ void fc3_kernel(const float* __restrict__ h2,
                           const float* __restrict__ L3, const float* __restrict__ L3b,
                           float* __restrict__ out) {
  int w = blockIdx.x * 4 + (threadIdx.x >> 6);   // 0..79
  int lane = threadIdx.x & 63;
  int b = w / 10, o = w - b * 10;
  float4 wv = *(const float4*)&L3[(size_t)o * 256 + lane * 4];
  float4 hv = *(const float4*)&h2[b * 256 + lane * 4];
  float s = wv.x * hv.x + wv.y * hv.y + wv.z * hv.z + wv.w * hv.w;
#pragma unroll
  for (int off = 32; off > 0; off >>= 1) s += __shfl_down(s, off);
  if (lane == 0) out[b * 10 + o] = s + L3b[o];
}

// ---------------------------------------------------------------- launch
extern "C" void kernel_launch(void* const* d_in, const int* in_sizes, int n_in,
                              void* d_out, int out_size, void* d_ws, size_t ws_size,
                              hipStream_t stream) {
  const float* x   = (const float*)d_in[0];
  const float* W1  = (const float*)d_in[1];
  const float* g1  = (const float*)d_in[2];
  const float* b1  = (const float*)d_in[3];
  const float* W2  = (const float*)d_in[4];
  const float* g2  = (const float*)d_in[5];
  const float* b2  = (const float*)d_in[6];
  const float* W3  = (const float*)d_in[7];
  const float* g3  = (const float*)d_in[8];
  const float* b3  = (const float*)d_in[9];
  const float* W4  = (const float*)d_in[10];
  const float* g4  = (const float*)d_in[11];
  const float* b4  = (const float*)d_in[12];
  const float* W5  = (const float*)d_in[13];
  const float* g5  = (const float*)d_in[14];
  const float* b5  = (const float*)d_in[15];
  const float* L1  = (const float*)d_in[16];
  const float* g6  = (const float*)d_in[17];
  const float* b6  = (const float*)d_in[18];
  const float* L2  = (const float*)d_in[19];
  const float* L2b = (const float*)d_in[20];
  const float* g7  = (const float*)d_in[21];
  const float* b7  = (const float*)d_in[22];
  const float* L3  = (const float*)d_in[23];
  const float* L3b = (const float*)d_in[24];
  float* out = (float*)d_out;

  // ---- workspace layout (bytes) — no fp32 xc
  char* p = (char*)d_ws;
  float* xx = (float*)p;          p += 16384 * 4;
  int*   idx = (int*)p;           p += (size_t)16384 * KNN_K * 4; // 1.31 MB
  float* wp = (float*)p;          p += 2 * 64 * 3 * 4 + 64;       // layer1 fp32 W'
  _Float16* wph = (_Float16*)p;   p += (size_t)512 * 128 * 2;
  _Float16* wpl = (_Float16*)p;   p += (size_t)512 * 128 * 2;
  _Float16* Xh = (_Float16*)p;    p += (size_t)16384 * 128 * 2;   // 4.19 MB
  _Float16* Xl = (_Float16*)p;    p += (size_t)16384 * 128 * 2;
  _Float16* xch = (_Float16*)p;   p += (size_t)16384 * 512 * 2;   // 16.78 MB dedicated
  float* gvec = (float*)p;        p += BATCH * 2048 * 4;          // 64 KB
  float* h1g  = (float*)p;        p += BATCH * 512 * 4;
  float* h2g  = (float*)p;        p += BATCH * 256 * 4;
  char* region = p;
  size_t baseB = (size_t)(region - (char*)d_ws);

  // region users: D (NB*16.78MB) | uv (33.55MB) | w5h+pools (~1.2MB)
  // NB capped at 2: D stays 33.5 MB -> LLC-resident between dist (producer)
  // and topk (consumer); r7 counters showed NB=8's 134 MB D was HBM-write-
  // bound in dist (2.9 TB/s WRITE) and re-fetched from HBM in topk.
  const size_t dB1 = (size_t)N_PTS * N_PTS * 4;
  const size_t uvB = (size_t)16384 * 512 * 4;
  int NB = 1;
  for (int cand = 2; cand >= 1; cand >>= 1) {
    size_t need = (size_t)cand * dB1 > uvB ? (size_t)cand * dB1 : uvB;
    if (baseB + need <= ws_size) { NB = cand; break; }
  }

  float* D  = (float*)region;
  float* uv = (float*)region;
  _Float16* w5h = (_Float16*)region;                 // after uv dead
  float* pmax = (float*)(w5h + (size_t)1024 * 512);
  float* psum = pmax + (size_t)BATCH * 16 * 1024;

  const int NPTS_TOT = BATCH * N_PTS;            // 16384

  // ================= layer 1: x (C=3) -> xch[:,0:64] + Xh/Xl/xx (no D)
  sqnorm_kernel<<<(NPTS_TOT + 255) / 256, 256, 0, stream>>>(x, 3, 3, xx);
  topk3_kernel<<<BATCH * 512, 256, 0, stream>>>(x, xx, idx);
  prep_wp3_kernel<<<2, 256, 0, stream>>>(W1, wp, 64, 3);
  gemm_uv3_kernel<<<(NPTS_TOT * 128 + 255) / 256, 256, 0, stream>>>(x, wp, uv);
  edge_max_kernel<64, true><<<NPTS_TOT / 4, 256, 0, stream>>>(
      uv, idx, g1, b1, xch + 0, Xh, Xl, xx);

  // ================= layer 2: x1 (C=64) -> xch[:,64:128] + Xh/Xl/xx
  for (int b0 = 0; b0 < BATCH; b0 += NB) {
    dist_mfma_kernel<64><<<NB * 256, 256, 0, stream>>>(Xh, Xl, xx, b0, D);
    topk_kernel<<<NB * N_PTS / 4, 256, 0, stream>>>(D, b0, idx);
  }
  prep_wpf16_kernel<<<(2 * 64 * 64 + 255) / 256, 256, 0, stream>>>(W2, wph, wpl, 64, 64);
  uv_mfma_kernel<64><<<1 * 128, 256, 0, stream>>>(Xh, Xl, wph, wpl, uv, 128);
  edge_max_kernel<64, true><<<NPTS_TOT / 4, 256, 0, stream>>>(
      uv, idx, g2, b2, xch + 64, Xh, Xl, xx);

  // ================= layer 3: x2 (C=64) -> xch[:,128:256] + Xh/Xl/xx (128-wide)
  for (int b0 = 0; b0 < BATCH; b0 += NB) {
    dist_mfma_kernel<64><<<NB * 256, 256, 0, stream>>>(Xh, Xl, xx, b0, D);
    topk_kernel<<<NB * N_PTS / 4, 256, 0, stream>>>(D, b0, idx);
  }
  prep_wpf16_kernel<<<(2 * 128 * 64 + 255) / 256, 256, 0, stream>>>(W3, wph, wpl, 128, 64);
  uv_mfma_kernel<64><<<2 * 128, 256, 0, stream>>>(Xh, Xl, wph, wpl, uv, 256);
  edge_max_kernel<128, true><<<NPTS_TOT / 2, 256, 0, stream>>>(
      uv, idx, g3, b3, xch + 128, Xh, Xl, xx);

  // ================= layer 4: x3 (C=128) -> xch[:,256:512] only
  for (int b0 = 0; b0 < BATCH; b0 += NB) {
    dist_mfma_kernel<128><<<NB * 256, 256, 0, stream>>>(Xh, Xl, xx, b0, D);
    topk_kernel<<<NB * N_PTS / 4, 256, 0, stream>>>(D, b0, idx);
  }
  prep_wpf16_kernel<<<(2 * 256 * 128 + 255) / 256, 256, 0, stream>>>(W4, wph, wpl, 256, 128);
  uv_mfma_kernel<128><<<4 * 128, 256, 0, stream>>>(Xh, Xl, wph, wpl, uv, 512);
  edge_max_kernel<256, false><<<NPTS_TOT, 256, 0, stream>>>(
      uv, idx, g4, b4, xch + 256, nullptr, nullptr, nullptr);

  // ================= W5 (f16 MFMA) + pooling, GEMV head
  cvt_f16_kernel<<<(1024 * 512 / 4 + 255) / 256, 256, 0, stream>>>(W5, w5h, 1024 * 512 / 4);
  w5_mfma_kernel<<<128 * 8, 256, 0, stream>>>(xch, w5h, g5, b5, pmax, psum);
  pool_kernel<<<32, 256, 0, stream>>>(pmax, psum, gvec);
  fc1_kernel<<<128, 256, 0, stream>>>(gvec, L1, g6, b6, h1g);
  fc2_kernel<<<512, 256, 0, stream>>>(h1g, L2, L2b, g7, b7, h2g);
  fc3_kernel<<<20, 256, 0, stream>>>(h2g, L3, L3b, out);
}

// Round 14
// 610.439 us; speedup vs baseline: 1.2303x; 1.2303x over previous
//
#include <hip/hip_runtime.h>
#include <cfloat>

#define N_PTS 2048
#define BATCH 8
#define KNN_K 20
#define XC_CH 512

constexpr float BN_SCALE_F = 0.9999950000374997f; // 1/sqrt(1+1e-5)

typedef _Float16 h8 __attribute__((ext_vector_type(8)));
typedef _Float16 h4v __attribute__((ext_vector_type(4)));
typedef float f32x4 __attribute__((ext_vector_type(4)));

// ---------------------------------------------------------------- sqnorm (layer-1 only, C=3)
__global__ void sqnorm_kernel(const float* __restrict__ in, int stride, int C,
                              float* __restrict__ xx) {
  int i = blockIdx.x * blockDim.x + threadIdx.x;
  if (i >= BATCH * N_PTS) return;
  const float* row = in + (size_t)i * stride;
  float s = 0.f;
  for (int c = 0; c < C; ++c) { float v = row[c]; s += v * v; }
  xx[i] = s;
}

// ---------------------------------------------------------------- fp32->f16 convert (packed, W5 only)
__global__ void cvt_f16_kernel(const float* __restrict__ in,
                               _Float16* __restrict__ out, int n4) {
  int t = blockIdx.x * 256 + threadIdx.x;
  if (t >= n4) return;
  float4 v = ((const float4*)in)[t];
  h4v o;
  o.x = (_Float16)v.x; o.y = (_Float16)v.y;
  o.z = (_Float16)v.z; o.w = (_Float16)v.w;
  ((h4v*)out)[t] = o;
}

// ---------------------------------------------------------------- selection core (proven r6/r7)
// v[32] per lane holds element gidx = i*64+lane; cached local top-3; 20 rounds
// of u64-key butterfly (sortable-f32<<32 | ~gidx: value desc, index asc on tie).
__device__ __forceinline__ void topk_select(float (&v)[32], int lane,
                                            int* __restrict__ knn_out, int out_base) {
  float t1 = -FLT_MAX, t2 = -FLT_MAX, t3 = -FLT_MAX;
  int i1 = -1, i2 = -1, i3 = -1;
#pragma unroll
  for (int i = 0; i < 32; ++i) {
    float val = v[i];
    bool g1 = val > t1, g2 = val > t2, g3 = val > t3;
    t3 = g2 ? t2 : (g3 ? val : t3);
    i3 = g2 ? i2 : (g3 ? i : i3);
    t2 = g1 ? t1 : (g2 ? val : t2);
    i2 = g1 ? i1 : (g2 ? i : i2);
    t1 = g1 ? val : t1;
    i1 = g1 ? i : i1;
  }
  unsigned consumed = 0u;

#pragma clang loop unroll(disable)
  for (int sel = 0; sel < KNN_K; ++sel) {
    if (i1 < 0) {                       // refill (rare: lane's 3rd+ win)
      float a1 = -FLT_MAX, a2 = -FLT_MAX, a3 = -FLT_MAX;
      int j1 = -1, j2 = -1, j3 = -1;
#pragma unroll
      for (int i = 0; i < 32; ++i) {
        float val = ((consumed >> i) & 1u) ? -FLT_MAX : v[i];
        bool g1 = val > a1, g2 = val > a2, g3 = val > a3;
        a3 = g2 ? a2 : (g3 ? val : a3);
        j3 = g2 ? j2 : (g3 ? i : j3);
        a2 = g1 ? a1 : (g2 ? val : a2);
        j2 = g1 ? j1 : (g2 ? i : j2);
        a1 = g1 ? val : a1;
        j1 = g1 ? i : j1;
      }
      t1 = a1; i1 = j1; t2 = a2; i2 = j2; t3 = a3; i3 = j3;
    }
    unsigned bits = __float_as_uint(t1);
    unsigned enc = bits ^ ((unsigned)((int)bits >> 31) | 0x80000000u);
    unsigned long long key =
        ((unsigned long long)enc << 32) | (unsigned)~(i1 * 64 + lane);
#pragma unroll
    for (int off = 32; off > 0; off >>= 1) {
      unsigned long long ok = __shfl_xor(key, off);
      if (ok > key) key = ok;
    }
    int bi = (int)~(unsigned)key;
    if (lane == 0) knn_out[out_base + sel] = bi;
    if ((bi & 63) == lane) {            // this lane's t1 won: pop cache
      consumed |= 1u << i1;
      t1 = t2; i1 = i2;
      t2 = t3; i2 = i3;
      t3 = -FLT_MAX; i3 = -1;
    }
  }
}

// ---------------------------------------------------------------- layer-1 knn: on-the-fly C=3 (no D)
// r9-proven form: 4096 blocks, ONE row per wave (no rr loop). r10/r11 showed
// any multi-row loop gets software-pipelined (two live v[32], VGPR 44->104,
// occupancy halves, 69->87us). Keep the single-row structure.
__global__ __launch_bounds__(256)
void topk3_kernel(const float* __restrict__ X, const float* __restrict__ xx,
                  int* __restrict__ knn_out) {
  __shared__ __align__(16) float colX[2048][4];
  int bl = blockIdx.x;
  int b = bl >> 9, rg = bl & 511;
  int row0 = rg * 4;
  int tid = threadIdx.x, wave = tid >> 6, lane = tid & 63;
  const float* Xb = X + (size_t)b * N_PTS * 3;
  const float* xxb = xx + b * N_PTS;
  for (int c = tid; c < 2048; c += 256) {
    colX[c][0] = Xb[c * 3];
    colX[c][1] = Xb[c * 3 + 1];
    colX[c][2] = Xb[c * 3 + 2];
    colX[c][3] = xxb[c];
  }
  __syncthreads();
  int r = row0 + wave;
  float4 rc = *(const float4*)&colX[r][0];
  float v[32];
#pragma unroll
  for (int i = 0; i < 32; ++i) {
    float4 cc = *(const float4*)&colX[i * 64 + lane][0];
    v[i] = 2.f * (rc.x * cc.x + rc.y * cc.y + rc.z * cc.z) - rc.w - cc.w;
  }
  topk_select(v, lane, knn_out, (b * N_PTS + r) * KNN_K);
}

// ---------------------------------------------------------------- top-20 from materialized D (layers 2-4)
__global__ void topk_kernel(const float* __restrict__ D, int b0,
                            int* __restrict__ knn_out) {
  int row = blockIdx.x * 4 + (threadIdx.x >> 6);
  int lane = threadIdx.x & 63;
  const float* dr = D + (size_t)row * N_PTS;
  float v[32];
#pragma unroll
  for (int i = 0; i < 32; ++i) v[i] = dr[i * 64 + lane];
  topk_select(v, lane, knn_out, (b0 * N_PTS + row) * KNN_K);
}

// ---------------------------------------------------------------- MFMA distance GEMM (split f16)
template<int K>
__global__ __launch_bounds__(256, 2)
void dist_mfma_kernel(const _Float16* __restrict__ Xh,
                      const _Float16* __restrict__ Xl,
                      const float* __restrict__ xx, int b0,
                      float* __restrict__ D) {
  constexpr int ST = 72;   // LDS row stride in f16 (64 + 8 pad)
  __shared__ __align__(16) _Float16 sm[4 * 128 * ST];
  _Float16* Ah = sm;
  _Float16* Al = sm + 128 * ST;
  _Float16* Bh = sm + 2 * 128 * ST;
  _Float16* Bl = sm + 3 * 128 * ST;

  int blk = blockIdx.x;
  int b_local = blk >> 8;
  int mblk = (blk >> 4) & 15, nblk = blk & 15;
  int b = b0 + b_local;
  int row0 = mblk * 128, col0 = nblk * 128;
  int tid = threadIdx.x;
  int wave = tid >> 6, lane = tid & 63;
  int wr = wave >> 1, wc = wave & 1;
  int quad = lane >> 4, l16 = lane & 15;

  const _Float16* XhB = Xh + (size_t)b * N_PTS * K;
  const _Float16* XlB = Xl + (size_t)b * N_PTS * K;

  f32x4 acc[4][4] = {};

  for (int k0 = 0; k0 < K; k0 += 64) {
    __syncthreads();
#pragma unroll
    for (int i = 0; i < 4; ++i) {
      int idx4 = tid + i * 256;
      int r = idx4 >> 3, c8 = idx4 & 7;
      int ko = k0 + c8 * 8;
      *(float4*)&Ah[r * ST + c8 * 8] = *(const float4*)&XhB[(size_t)(row0 + r) * K + ko];
      *(float4*)&Al[r * ST + c8 * 8] = *(const float4*)&XlB[(size_t)(row0 + r) * K + ko];
      *(float4*)&Bh[r * ST + c8 * 8] = *(const float4*)&XhB[(size_t)(col0 + r) * K + ko];
      *(float4*)&Bl[r * ST + c8 * 8] = *(const float4*)&XlB[(size_t)(col0 + r) * K + ko];
    }
    __syncthreads();
#pragma unroll
    for (int ks = 0; ks < 2; ++ks) {
      h8 bh[4], bl[4];
#pragma unroll
      for (int nt = 0; nt < 4; ++nt) {
        int off = (wc * 64 + nt * 16 + l16) * ST + ks * 32 + quad * 8;
        bh[nt] = *(const h8*)&Bh[off];
        bl[nt] = *(const h8*)&Bl[off];
      }
#pragma unroll
      for (int mt = 0; mt < 4; ++mt) {
        int off = (wr * 64 + mt * 16 + l16) * ST + ks * 32 + quad * 8;
        h8 ah = *(const h8*)&Ah[off];
        h8 al = *(const h8*)&Al[off];
#pragma unroll
        for (int nt = 0; nt < 4; ++nt) {
          acc[mt][nt] = __builtin_amdgcn_mfma_f32_16x16x32_f16(ah, bh[nt], acc[mt][nt], 0, 0, 0);
          acc[mt][nt] = __builtin_amdgcn_mfma_f32_16x16x32_f16(ah, bl[nt], acc[mt][nt], 0, 0, 0);
          acc[mt][nt] = __builtin_amdgcn_mfma_f32_16x16x32_f16(al, bh[nt], acc[mt][nt], 0, 0, 0);
        }
      }
    }
  }

  // epilogue: LDS transpose -> coalesced float4 stores with xx correction
  __syncthreads();
  float* S = (float*)sm;               // 128 x 132
#pragma unroll
  for (int mt = 0; mt < 4; ++mt)
#pragma unroll
    for (int nt = 0; nt < 4; ++nt)
#pragma unroll
      for (int i = 0; i < 4; ++i) {
        int rm = wr * 64 + mt * 16 + quad * 4 + i;
        int cn = wc * 64 + nt * 16 + l16;
        S[rm * 132 + cn] = 2.f * acc[mt][nt][i];
      }
  __syncthreads();
  const float* xxb = xx + b * N_PTS;
  float* Db = D + (size_t)b_local * N_PTS * N_PTS;
#pragma unroll
  for (int j = 0; j < 16; ++j) {
    int flat = j * 256 + tid;          // float4 index 0..4095
    int r = flat >> 5, c4 = (flat & 31) * 4;
    float xr = xxb[row0 + r];
    float4 v = *(const float4*)&S[r * 132 + c4];
    float4 xc4 = *(const float4*)&xxb[col0 + c4];
    float4 o = {v.x - xr - xc4.x, v.y - xr - xc4.y,
                v.z - xr - xc4.z, v.w - xr - xc4.w};
    *(float4*)&Db[(size_t)(row0 + r) * N_PTS + col0 + c4] = o;
  }
}

// ---------------------------------------------------------------- MFMA uv GEMM (split f16)
template<int K>
__global__ __launch_bounds__(256, 2)
void uv_mfma_kernel(const _Float16* __restrict__ Xh,
                    const _Float16* __restrict__ Xl,
                    const _Float16* __restrict__ Wph,
                    const _Float16* __restrict__ Wpl,
                    float* __restrict__ out, int NCOLS) {
  constexpr int ST = 72;
  __shared__ __align__(16) _Float16 sm[4 * 128 * ST];
  _Float16* Ah = sm;
  _Float16* Al = sm + 128 * ST;
  _Float16* Bh = sm + 2 * 128 * ST;
  _Float16* Bl = sm + 3 * 128 * ST;

  int nblk = blockIdx.x >> 7, mblk = blockIdx.x & 127;
  int row0 = mblk * 128, col0 = nblk * 128;
  int tid = threadIdx.x;
  int wave = tid >> 6, lane = tid & 63;
  int wr = wave >> 1, wc = wave & 1;
  int quad = lane >> 4, l16 = lane & 15;

  f32x4 acc[4][4] = {};

  for (int k0 = 0; k0 < K; k0 += 64) {
    __syncthreads();
#pragma unroll
    for (int i = 0; i < 4; ++i) {
      int idx4 = tid + i * 256;
      int r = idx4 >> 3, c8 = idx4 & 7;
      int ko = k0 + c8 * 8;
      *(float4*)&Ah[r * ST + c8 * 8] = *(const float4*)&Xh[(size_t)(row0 + r) * K + ko];
      *(float4*)&Al[r * ST + c8 * 8] = *(const float4*)&Xl[(size_t)(row0 + r) * K + ko];
      *(float4*)&Bh[r * ST + c8 * 8] = *(const float4*)&Wph[(size_t)(col0 + r) * K + ko];
      *(float4*)&Bl[r * ST + c8 * 8] = *(const float4*)&Wpl[(size_t)(col0 + r) * K + ko];
    }
    __syncthreads();
#pragma unroll
    for (int ks = 0; ks < 2; ++ks) {
      h8 bh[4], bl[4];
#pragma unroll
      for (int nt = 0; nt < 4; ++nt) {
        int off = (wc * 64 + nt * 16 + l16) * ST + ks * 32 + quad * 8;
        bh[nt] = *(const h8*)&Bh[off];
        bl[nt] = *(const h8*)&Bl[off];
      }
#pragma unroll
      for (int mt = 0; mt < 4; ++mt) {
        int off = (wr * 64 + mt * 16 + l16) * ST + ks * 32 + quad * 8;
        h8 ah = *(const h8*)&Ah[off];
        h8 al = *(const h8*)&Al[off];
#pragma unroll
        for (int nt = 0; nt < 4; ++nt) {
          acc[mt][nt] = __builtin_amdgcn_mfma_f32_16x16x32_f16(ah, bh[nt], acc[mt][nt], 0, 0, 0);
          acc[mt][nt] = __builtin_amdgcn_mfma_f32_16x16x32_f16(ah, bl[nt], acc[mt][nt], 0, 0, 0);
          acc[mt][nt] = __builtin_amdgcn_mfma_f32_16x16x32_f16(al, bh[nt], acc[mt][nt], 0, 0, 0);
        }
      }
    }
  }

  __syncthreads();
  float* S = (float*)sm;
#pragma unroll
  for (int mt = 0; mt < 4; ++mt)
#pragma unroll
    for (int nt = 0; nt < 4; ++nt)
#pragma unroll
      for (int i = 0; i < 4; ++i) {
        int rm = wr * 64 + mt * 16 + quad * 4 + i;
        int cn = wc * 64 + nt * 16 + l16;
        S[rm * 132 + cn] = acc[mt][nt][i];
      }
  __syncthreads();
#pragma unroll
  for (int j = 0; j < 16; ++j) {
    int flat = j * 256 + tid;
    int r = flat >> 5, c4 = (flat & 31) * 4;
    float4 v = *(const float4*)&S[r * 132 + c4];
    *(float4*)&out[(size_t)(row0 + r) * NCOLS + col0 + c4] = v;
  }
}

// ---------------------------------------------------------------- MFMA W5 GEMM + bn/lrelu + pooling
__global__ __launch_bounds__(256, 2)
void w5_mfma_kernel(const _Float16* __restrict__ xch,
                    const _Float16* __restrict__ w5h,
                    const float* __restrict__ g5,
                    const float* __restrict__ b5,
                    float* __restrict__ pmax, float* __restrict__ psum) {
  constexpr int ST = 72;
  __shared__ __align__(16) _Float16 sm[2 * 128 * ST];
  __shared__ float redm[2][128], reds[2][128];
  _Float16* Ah = sm;
  _Float16* Bh = sm + 128 * ST;

  int mblk = blockIdx.x >> 3, nblk = blockIdx.x & 7;
  int row0 = mblk * 128, o0 = nblk * 128;
  int tid = threadIdx.x;
  int wave = tid >> 6, lane = tid & 63;
  int wr = wave >> 1, wc = wave & 1;
  int quad = lane >> 4, l16 = lane & 15;

  f32x4 acc[4][4] = {};

  for (int k0 = 0; k0 < XC_CH; k0 += 64) {
    __syncthreads();
#pragma unroll
    for (int i = 0; i < 4; ++i) {       // 1024 (r,c8) pairs
      int idx4 = tid + i * 256;
      int r = idx4 >> 3, c8 = idx4 & 7;
      int ko = k0 + c8 * 8;
      *(float4*)&Ah[r * ST + c8 * 8] = *(const float4*)&xch[(size_t)(row0 + r) * XC_CH + ko];
      *(float4*)&Bh[r * ST + c8 * 8] = *(const float4*)&w5h[(size_t)(o0 + r) * XC_CH + ko];
    }
    __syncthreads();
#pragma unroll
    for (int ks = 0; ks < 2; ++ks) {
      h8 bh[4];
#pragma unroll
      for (int nt = 0; nt < 4; ++nt)
        bh[nt] = *(const h8*)&Bh[(wc * 64 + nt * 16 + l16) * ST + ks * 32 + quad * 8];
#pragma unroll
      for (int mt = 0; mt < 4; ++mt) {
        h8 ah = *(const h8*)&Ah[(wr * 64 + mt * 16 + l16) * ST + ks * 32 + quad * 8];
#pragma unroll
        for (int nt = 0; nt < 4; ++nt)
          acc[mt][nt] = __builtin_amdgcn_mfma_f32_16x16x32_f16(ah, bh[nt], acc[mt][nt], 0, 0, 0);
      }
    }
  }

#pragma unroll
  for (int nt = 0; nt < 4; ++nt) {
    int gcol = o0 + wc * 64 + nt * 16 + l16;
    float g = g5[gcol], be = b5[gcol];
    float pm = -FLT_MAX, ps = 0.f;
#pragma unroll
    for (int mt = 0; mt < 4; ++mt)
#pragma unroll
      for (int i = 0; i < 4; ++i) {
        float y = g * (acc[mt][nt][i] * BN_SCALE_F) + be;
        y = (y > 0.f) ? y : 0.2f * y;
        pm = fmaxf(pm, y);
        ps += y;
      }
#pragma unroll
    for (int off = 16; off <= 32; off <<= 1) {
      pm = fmaxf(pm, __shfl_xor(pm, off));
      ps += __shfl_xor(ps, off);
    }
    if (quad == 0) {
      redm[wr][wc * 64 + nt * 16 + l16] = pm;
      reds[wr][wc * 64 + nt * 16 + l16] = ps;
    }
  }
  __syncthreads();
  if (tid < 128) {
    float m = fmaxf(redm[0][tid], redm[1][tid]);
    float s = reds[0][tid] + reds[1][tid];
    int bb = mblk >> 4, ch = mblk & 15;
    size_t off = (size_t)(bb * 16 + ch) * 1024 + o0 + tid;
    pmax[off] = m;
    psum[off] = s;
  }
}

// ---------------------------------------------------------------- W' prep (layer1, fp32)
__global__ void prep_wp3_kernel(const float* __restrict__ W,
                                float* __restrict__ Wp, int O, int C) {
  int t = blockIdx.x * 256 + threadIdx.x;
  if (t >= 2 * O * C) return;
  int o = t / C, c = t % C;
  Wp[t] = (o < O) ? W[(size_t)o * 2 * C + c]
                  : (W[(size_t)(o - O) * 2 * C + C + c] -
                     W[(size_t)(o - O) * 2 * C + c]);
}

// ---------------------------------------------------------------- W' prep (f16 hi/lo)
__global__ void prep_wpf16_kernel(const float* __restrict__ W,
                                  _Float16* __restrict__ Wph,
                                  _Float16* __restrict__ Wpl, int O, int C) {
  int t = blockIdx.x * 256 + threadIdx.x;
  if (t >= 2 * O * C) return;
  int o = t / C, c = t % C;
  float val = (o < O) ? W[(size_t)o * 2 * C + c]
                      : (W[(size_t)(o - O) * 2 * C + C + c] -
                         W[(size_t)(o - O) * 2 * C + c]);
  _Float16 hv = (_Float16)val;
  Wph[t] = hv;
  Wpl[t] = (_Float16)(val - (float)hv);
}

// ---------------------------------------------------------------- layer-1 uv (K=3, fp32)
__global__ void gemm_uv3_kernel(const float* __restrict__ x,
                                const float* __restrict__ Wp,
                                float* __restrict__ out) {
  int t = blockIdx.x * 256 + threadIdx.x;
  if (t >= BATCH * N_PTS * 128) return;
  int n = t >> 7, o = t & 127;
  const float* xr = x + (size_t)n * 3;
  const float* wr = Wp + (size_t)o * 3;
  out[t] = xr[0] * wr[0] + xr[1] * wr[1] + xr[2] * wr[2];
}

// ---------------------------------------------------------------- edge gather+max, fused next-layer prep
// Writes: xch slice (f16, stride XC_CH) always; if WS also the packed hi/lo
// split (Xh/Xl, stride O) and xx[n] = sum_o mx^2 (replaces split_sq_kernel).
template<int O, bool WS>
__global__ void edge_max_kernel(const float* __restrict__ uv,
                                const int* __restrict__ knn_idx,
                                const float* __restrict__ gamma,
                                const float* __restrict__ beta,
                                _Float16* __restrict__ xch_out,
                                _Float16* __restrict__ Xh,
                                _Float16* __restrict__ Xl,
                                float* __restrict__ xx) {
  constexpr int P = 256 / O;
  int tid = threadIdx.x;
  int p = tid / O, o = tid % O;
  int n = blockIdx.x * P + p;
  int b = n / N_PTS;
  float v = uv[(size_t)n * (2 * O) + O + o];
  float g = gamma[o], be = beta[o];
  const int* ir = knn_idx + (size_t)n * KNN_K;
  int mk[KNN_K];
#pragma unroll
  for (int k = 0; k < KNN_K; ++k) mk[k] = ir[k];
  float mx = -FLT_MAX;
#pragma unroll
  for (int k = 0; k < KNN_K; ++k) {
    float u = uv[(size_t)(b * N_PTS + mk[k]) * (2 * O) + o];
    float y = g * ((u + v) * BN_SCALE_F) + be;
    y = (y > 0.f) ? y : 0.2f * y;
    mx = fmaxf(mx, y);
  }
  xch_out[(size_t)n * XC_CH + o] = (_Float16)mx;
  if constexpr (WS) {
    _Float16 hv = (_Float16)mx;
    Xh[(size_t)n * O + o] = hv;
    Xl[(size_t)n * O + o] = (_Float16)(mx - (float)hv);
    float sq = mx * mx;
    if constexpr (O == 64) {
#pragma unroll
      for (int off = 32; off > 0; off >>= 1) sq += __shfl_xor(sq, off);
      if ((tid & 63) == 0) xx[n] = sq;
    } else {  // O == 128: two waves per row
      __shared__ float sred[4];
#pragma unroll
      for (int off = 32; off > 0; off >>= 1) sq += __shfl_xor(sq, off);
      if ((tid & 63) == 0) sred[tid >> 6] = sq;
      __syncthreads();
      if (tid < P) xx[blockIdx.x * P + tid] = sred[tid * 2] + sred[tid * 2 + 1];
    }
  }
}

// ---------------------------------------------------------------- head
__global__ void pool_kernel(const float* __restrict__ pmax,
                            const float* __restrict__ psum,
                            float* __restrict__ gvec) {
  int t = blockIdx.x * 256 + threadIdx.x;   // 8192 threads
  int b = t >> 10, o = t & 1023;
  float mx = -FLT_MAX, sm = 0.f;
#pragma unroll
  for (int ch = 0; ch < 16; ++ch) {
    size_t idx = (size_t)(b * 16 + ch) * 1024 + o;
    mx = fmaxf(mx, pmax[idx]);
    sm += psum[idx];
  }
  gvec[b * 2048 + o] = mx;
  gvec[b * 2048 + 1024 + o] = sm * (1.f / 2048.f);
}

__global__ void fc1_kernel(const float* __restrict__ gvec,
                           const float* __restrict__ L1,
                           const float* __restrict__ g6, const float* __restrict__ b6,
                           float* __restrict__ h1) {
  int o = blockIdx.x * 4 + (threadIdx.x >> 6);   // 0..511
  int lane = threadIdx.x & 63;
  float4 w[8];
#pragma unroll
  for (int i = 0; i < 8; ++i)
    w[i] = *(const float4*)&L1[(size_t)o * 2048 + i * 256 + lane * 4];
  float g = g6[o], be = b6[o];
  for (int b = 0; b < BATCH; ++b) {
    float s = 0.f;
#pragma unroll
    for (int i = 0; i < 8; ++i) {
      float4 v = *(const float4*)&gvec[b * 2048 + i * 256 + lane * 4];
      s += w[i].x * v.x + w[i].y * v.y + w[i].z * v.z + w[i].w * v.w;
    }
#pragma unroll
    for (int off = 32; off > 0; off >>= 1) s += __shfl_down(s, off);
    if (lane == 0) {
      float y = g * (s * BN_SCALE_F) + be;
      h1[b * 512 + o] = (y > 0.f) ? y : 0.2f * y;
    }
  }
}

__global__ void fc2_kernel(const float* __restrict__ h1,
                           const float* __restrict__ L2, const float* __restrict__ L2b,
                           const float* __restrict__ g7, const float* __restrict__ b7,
                           float* __restrict__ h2) {
  int w = blockIdx.x * 4 + (threadIdx.x >> 6);   // 0..2047
  int lane = threadIdx.x & 63;
  int b = w >> 8, o = w & 255;
  float s = 0.f;
#pragma unroll
  for (int i = 0; i < 2; ++i) {
    float4 wv = *(const float4*)&L2[(size_t)o * 512 + i * 256 + lane * 4];
    float4 hv = *(const float4*)&h1[b * 512 + i * 256 + lane * 4];
    s += wv.x * hv.x + wv.y * hv.y + wv.z * hv.z + wv.w * hv.w;
  }
#pragma unroll
  for (int off = 32; off > 0; off >>= 1) s += __shfl_down(s, off);
  if (lane == 0) {
    float y = g7[o] * ((s + L2b[o]) * BN_SCALE_F) + b7[o];
    h2[b * 256 + o] = (y > 0.f) ? y : 0.2f * y;
  }
}

__global__ void fc3_kernel(const float* __restrict__ h2,
                           const float* __restrict__ L3, const float* __restrict__ L3b,
                           float* __restrict__ out) {
  int w = blockIdx.x * 4 + (threadIdx.x >> 6);   // 0..79
  int lane = threadIdx.x & 63;
  int b = w / 10, o = w - b * 10;
  float4 wv = *(const float4*)&L3[(size_t)o * 256 + lane * 4];
  float4 hv = *(const float4*)&h2[b * 256 + lane * 4];
  float s = wv.x * hv.x + wv.y * hv.y + wv.z * hv.z + wv.w * hv.w;
#pragma unroll
  for (int off = 32; off > 0; off >>= 1) s += __shfl_down(s, off);
  if (lane == 0) out[b * 10 + o] = s + L3b[o];
}

// ---------------------------------------------------------------- launch
extern "C" void kernel_launch(void* const* d_in, const int* in_sizes, int n_in,
                              void* d_out, int out_size, void* d_ws, size_t ws_size,
                              hipStream_t stream) {
  const float* x   = (const float*)d_in[0];
  const float* W1  = (const float*)d_in[1];
  const float* g1  = (const float*)d_in[2];
  const float* b1  = (const float*)d_in[3];
  const float* W2  = (const float*)d_in[4];
  const float* g2  = (const float*)d_in[5];
  const float* b2  = (const float*)d_in[6];
  const float* W3  = (const float*)d_in[7];
  const float* g3  = (const float*)d_in[8];
  const float* b3  = (const float*)d_in[9];
  const float* W4  = (const float*)d_in[10];
  const float* g4  = (const float*)d_in[11];
  const float* b4  = (const float*)d_in[12];
  const float* W5  = (const float*)d_in[13];
  const float* g5  = (const float*)d_in[14];
  const float* b5  = (const float*)d_in[15];
  const float* L1  = (const float*)d_in[16];
  const float* g6  = (const float*)d_in[17];
  const float* b6  = (const float*)d_in[18];
  const float* L2  = (const float*)d_in[19];
  const float* L2b = (const float*)d_in[20];
  const float* g7  = (const float*)d_in[21];
  const float* b7  = (const float*)d_in[22];
  const float* L3  = (const float*)d_in[23];
  const float* L3b = (const float*)d_in[24];
  float* out = (float*)d_out;

  // ---- workspace layout (bytes) — no fp32 xc
  char* p = (char*)d_ws;
  float* xx = (float*)p;          p += 16384 * 4;
  int*   idx = (int*)p;           p += (size_t)16384 * KNN_K * 4; // 1.31 MB
  float* wp = (float*)p;          p += 2 * 64 * 3 * 4 + 64;       // layer1 fp32 W'
  _Float16* wph = (_Float16*)p;   p += (size_t)512 * 128 * 2;
  _Float16* wpl = (_Float16*)p;   p += (size_t)512 * 128 * 2;
  _Float16* Xh = (_Float16*)p;    p += (size_t)16384 * 128 * 2;   // 4.19 MB
  _Float16* Xl = (_Float16*)p;    p += (size_t)16384 * 128 * 2;
  _Float16* xch = (_Float16*)p;   p += (size_t)16384 * 512 * 2;   // 16.78 MB dedicated
  float* gvec = (float*)p;        p += BATCH * 2048 * 4;          // 64 KB
  float* h1g  = (float*)p;        p += BATCH * 512 * 4;
  float* h2g  = (float*)p;        p += BATCH * 256 * 4;
  char* region = p;
  size_t baseB = (size_t)(region - (char*)d_ws);

  // region users: D (NB*16.78MB) | uv (33.55MB) | w5h+pools (~1.2MB)
  // NB back to up-to-8 (r12 state): r13's NB=2 cap regressed 603->751us —
  // the 4x dependent launch pairs' serialization cost outweighed any cache
  // effect (D fits LLC at NB=8 anyway).
  const size_t dB1 = (size_t)N_PTS * N_PTS * 4;
  const size_t uvB = (size_t)16384 * 512 * 4;
  int NB = 1;
  for (int cand = 8; cand >= 1; cand >>= 1) {
    size_t need = (size_t)cand * dB1 > uvB ? (size_t)cand * dB1 : uvB;
    if (baseB + need <= ws_size) { NB = cand; break; }
  }

  float* D  = (float*)region;
  float* uv = (float*)region;
  _Float16* w5h = (_Float16*)region;                 // after uv dead
  float* pmax = (float*)(w5h + (size_t)1024 * 512);
  float* psum = pmax + (size_t)BATCH * 16 * 1024;

  const int NPTS_TOT = BATCH * N_PTS;            // 16384

  // ================= layer 1: x (C=3) -> xch[:,0:64] + Xh/Xl/xx (no D)
  sqnorm_kernel<<<(NPTS_TOT + 255) / 256, 256, 0, stream>>>(x, 3, 3, xx);
  topk3_kernel<<<BATCH * 512, 256, 0, stream>>>(x, xx, idx);
  prep_wp3_kernel<<<2, 256, 0, stream>>>(W1, wp, 64, 3);
  gemm_uv3_kernel<<<(NPTS_TOT * 128 + 255) / 256, 256, 0, stream>>>(x, wp, uv);
  edge_max_kernel<64, true><<<NPTS_TOT / 4, 256, 0, stream>>>(
      uv, idx, g1, b1, xch + 0, Xh, Xl, xx);

  // ================= layer 2: x1 (C=64) -> xch[:,64:128] + Xh/Xl/xx
  for (int b0 = 0; b0 < BATCH; b0 += NB) {
    dist_mfma_kernel<64><<<NB * 256, 256, 0, stream>>>(Xh, Xl, xx, b0, D);
    topk_kernel<<<NB * N_PTS / 4, 256, 0, stream>>>(D, b0, idx);
  }
  prep_wpf16_kernel<<<(2 * 64 * 64 + 255) / 256, 256, 0, stream>>>(W2, wph, wpl, 64, 64);
  uv_mfma_kernel<64><<<1 * 128, 256, 0, stream>>>(Xh, Xl, wph, wpl, uv, 128);
  edge_max_kernel<64, true><<<NPTS_TOT / 4, 256, 0, stream>>>(
      uv, idx, g2, b2, xch + 64, Xh, Xl, xx);

  // ================= layer 3: x2 (C=64) -> xch[:,128:256] + Xh/Xl/xx (128-wide)
  for (int b0 = 0; b0 < BATCH; b0 += NB) {
    dist_mfma_kernel<64><<<NB * 256, 256, 0, stream>>>(Xh, Xl, xx, b0, D);
    topk_kernel<<<NB * N_PTS / 4, 256, 0, stream>>>(D, b0, idx);
  }
  prep_wpf16_kernel<<<(2 * 128 * 64 + 255) / 256, 256, 0, stream>>>(W3, wph, wpl, 128, 64);
  uv_mfma_kernel<64><<<2 * 128, 256, 0, stream>>>(Xh, Xl, wph, wpl, uv, 256);
  edge_max_kernel<128, true><<<NPTS_TOT / 2, 256, 0, stream>>>(
      uv, idx, g3, b3, xch + 128, Xh, Xl, xx);

  // ================= layer 4: x3 (C=128) -> xch[:,256:512] only
  for (int b0 = 0; b0 < BATCH; b0 += NB) {
    dist_mfma_kernel<128><<<NB * 256, 256, 0, stream>>>(Xh, Xl, xx, b0, D);
    topk_kernel<<<NB * N_PTS / 4, 256, 0, stream>>>(D, b0, idx);
  }
  prep_wpf16_kernel<<<(2 * 256 * 128 + 255) / 256, 256, 0, stream>>>(W4, wph, wpl, 256, 128);
  uv_mfma_kernel<128><<<4 * 128, 256, 0, stream>>>(Xh, Xl, wph, wpl, uv, 512);
  edge_max_kernel<256, false><<<NPTS_TOT, 256, 0, stream>>>(
      uv, idx, g4, b4, xch + 256, nullptr, nullptr, nullptr);

  // ================= W5 (f16 MFMA) + pooling, GEMV head
  cvt_f16_kernel<<<(1024 * 512 / 4 + 255) / 256, 256, 0, stream>>>(W5, w5h, 1024 * 512 / 4);
  w5_mfma_kernel<<<128 * 8, 256, 0, stream>>>(xch, w5h, g5, b5, pmax, psum);
  pool_kernel<<<32, 256, 0, stream>>>(pmax, psum, gvec);
  fc1_kernel<<<128, 256, 0, stream>>>(gvec, L1, g6, b6, h1g);
  fc2_kernel<<<512, 256, 0, stream>>>(h1g, L2, L2b, g7, b7, h2g);
  fc3_kernel<<<20, 256, 0, stream>>>(h2g, L3, L3b, out);
}

// Round 15
// 591.399 us; speedup vs baseline: 1.2699x; 1.0322x over previous
//
#include <hip/hip_runtime.h>
#include <cfloat>

#define N_PTS 2048
#define BATCH 8
#define KNN_K 20
#define XC_CH 512

constexpr float BN_SCALE_F = 0.9999950000374997f; // 1/sqrt(1+1e-5)

typedef _Float16 h8 __attribute__((ext_vector_type(8)));
typedef _Float16 h4v __attribute__((ext_vector_type(4)));
typedef float f32x4 __attribute__((ext_vector_type(4)));

// ---------------------------------------------------------------- fp32->f16 convert (packed, W5 only)
__global__ void cvt_f16_kernel(const float* __restrict__ in,
                               _Float16* __restrict__ out, int n4) {
  int t = blockIdx.x * 256 + threadIdx.x;
  if (t >= n4) return;
  float4 v = ((const float4*)in)[t];
  h4v o;
  o.x = (_Float16)v.x; o.y = (_Float16)v.y;
  o.z = (_Float16)v.z; o.w = (_Float16)v.w;
  ((h4v*)out)[t] = o;
}

// ---------------------------------------------------------------- selection core (proven r6/r7)
// v[32] per lane holds element gidx = i*64+lane; cached local top-3; 20 rounds
// of u64-key butterfly (sortable-f32<<32 | ~gidx: value desc, index asc on tie).
__device__ __forceinline__ void topk_select(float (&v)[32], int lane,
                                            int* __restrict__ knn_out, int out_base) {
  float t1 = -FLT_MAX, t2 = -FLT_MAX, t3 = -FLT_MAX;
  int i1 = -1, i2 = -1, i3 = -1;
#pragma unroll
  for (int i = 0; i < 32; ++i) {
    float val = v[i];
    bool g1 = val > t1, g2 = val > t2, g3 = val > t3;
    t3 = g2 ? t2 : (g3 ? val : t3);
    i3 = g2 ? i2 : (g3 ? i : i3);
    t2 = g1 ? t1 : (g2 ? val : t2);
    i2 = g1 ? i1 : (g2 ? i : i2);
    t1 = g1 ? val : t1;
    i1 = g1 ? i : i1;
  }
  unsigned consumed = 0u;

#pragma clang loop unroll(disable)
  for (int sel = 0; sel < KNN_K; ++sel) {
    if (i1 < 0) {                       // refill (rare: lane's 3rd+ win)
      float a1 = -FLT_MAX, a2 = -FLT_MAX, a3 = -FLT_MAX;
      int j1 = -1, j2 = -1, j3 = -1;
#pragma unroll
      for (int i = 0; i < 32; ++i) {
        float val = ((consumed >> i) & 1u) ? -FLT_MAX : v[i];
        bool g1 = val > a1, g2 = val > a2, g3 = val > a3;
        a3 = g2 ? a2 : (g3 ? val : a3);
        j3 = g2 ? j2 : (g3 ? i : j3);
        a2 = g1 ? a1 : (g2 ? val : a2);
        j2 = g1 ? j1 : (g2 ? i : j2);
        a1 = g1 ? val : a1;
        j1 = g1 ? i : j1;
      }
      t1 = a1; i1 = j1; t2 = a2; i2 = j2; t3 = a3; i3 = j3;
    }
    unsigned bits = __float_as_uint(t1);
    unsigned enc = bits ^ ((unsigned)((int)bits >> 31) | 0x80000000u);
    unsigned long long key =
        ((unsigned long long)enc << 32) | (unsigned)~(i1 * 64 + lane);
#pragma unroll
    for (int off = 32; off > 0; off >>= 1) {
      unsigned long long ok = __shfl_xor(key, off);
      if (ok > key) key = ok;
    }
    int bi = (int)~(unsigned)key;
    if (lane == 0) knn_out[out_base + sel] = bi;
    if ((bi & 63) == lane) {            // this lane's t1 won: pop cache
      consumed |= 1u << i1;
      t1 = t2; i1 = i2;
      t2 = t3; i2 = i3;
      t3 = -FLT_MAX; i3 = -1;
    }
  }
}

// ---------------------------------------------------------------- layer-1 knn: on-the-fly C=3 (no D)
// 512-thread blocks, 8 rows/block, ONE row per wave (keeps the r9 invariant:
// no multi-row loop around a live v[32] — r10/r11 showed those get software-
// pipelined into two register copies). 8 waves/block -> 4 blocks/CU hits the
// 32-wave cap (100% occupancy budget vs 20/32 at 256 threads); staging halves.
// sqnorm fused into staging (same association order: (x2+y2)+z2).
__global__ __launch_bounds__(512)
void topk3_kernel(const float* __restrict__ X, int* __restrict__ knn_out) {
  __shared__ __align__(16) float colX[2048][4];
  int bl = blockIdx.x;
  int b = bl >> 8, rg = bl & 255;
  int row0 = rg * 8;
  int tid = threadIdx.x, wave = tid >> 6, lane = tid & 63;
  const float* Xb = X + (size_t)b * N_PTS * 3;
  for (int c = tid; c < 2048; c += 512) {
    float vx = Xb[c * 3], vy = Xb[c * 3 + 1], vz = Xb[c * 3 + 2];
    colX[c][0] = vx;
    colX[c][1] = vy;
    colX[c][2] = vz;
    colX[c][3] = vx * vx + vy * vy + vz * vz;
  }
  __syncthreads();
  int r = row0 + wave;
  float4 rc = *(const float4*)&colX[r][0];
  float v[32];
#pragma unroll
  for (int i = 0; i < 32; ++i) {
    float4 cc = *(const float4*)&colX[i * 64 + lane][0];
    v[i] = 2.f * (rc.x * cc.x + rc.y * cc.y + rc.z * cc.z) - rc.w - cc.w;
  }
  topk_select(v, lane, knn_out, (b * N_PTS + r) * KNN_K);
}

// ---------------------------------------------------------------- top-20 from materialized D (layers 2-4)
__global__ void topk_kernel(const float* __restrict__ D, int b0,
                            int* __restrict__ knn_out) {
  int row = blockIdx.x * 4 + (threadIdx.x >> 6);
  int lane = threadIdx.x & 63;
  const float* dr = D + (size_t)row * N_PTS;
  float v[32];
#pragma unroll
  for (int i = 0; i < 32; ++i) v[i] = dr[i * 64 + lane];
  topk_select(v, lane, knn_out, (b0 * N_PTS + row) * KNN_K);
}

// ---------------------------------------------------------------- MFMA distance GEMM (split f16)
template<int K>
__global__ __launch_bounds__(256, 2)
void dist_mfma_kernel(const _Float16* __restrict__ Xh,
                      const _Float16* __restrict__ Xl,
                      const float* __restrict__ xx, int b0,
                      float* __restrict__ D) {
  constexpr int ST = 72;   // LDS row stride in f16 (64 + 8 pad)
  __shared__ __align__(16) _Float16 sm[4 * 128 * ST];
  _Float16* Ah = sm;
  _Float16* Al = sm + 128 * ST;
  _Float16* Bh = sm + 2 * 128 * ST;
  _Float16* Bl = sm + 3 * 128 * ST;

  int blk = blockIdx.x;
  int b_local = blk >> 8;
  int mblk = (blk >> 4) & 15, nblk = blk & 15;
  int b = b0 + b_local;
  int row0 = mblk * 128, col0 = nblk * 128;
  int tid = threadIdx.x;
  int wave = tid >> 6, lane = tid & 63;
  int wr = wave >> 1, wc = wave & 1;
  int quad = lane >> 4, l16 = lane & 15;

  const _Float16* XhB = Xh + (size_t)b * N_PTS * K;
  const _Float16* XlB = Xl + (size_t)b * N_PTS * K;

  f32x4 acc[4][4] = {};

  for (int k0 = 0; k0 < K; k0 += 64) {
    __syncthreads();
#pragma unroll
    for (int i = 0; i < 4; ++i) {
      int idx4 = tid + i * 256;
      int r = idx4 >> 3, c8 = idx4 & 7;
      int ko = k0 + c8 * 8;
      *(float4*)&Ah[r * ST + c8 * 8] = *(const float4*)&XhB[(size_t)(row0 + r) * K + ko];
      *(float4*)&Al[r * ST + c8 * 8] = *(const float4*)&XlB[(size_t)(row0 + r) * K + ko];
      *(float4*)&Bh[r * ST + c8 * 8] = *(const float4*)&XhB[(size_t)(col0 + r) * K + ko];
      *(float4*)&Bl[r * ST + c8 * 8] = *(const float4*)&XlB[(size_t)(col0 + r) * K + ko];
    }
    __syncthreads();
#pragma unroll
    for (int ks = 0; ks < 2; ++ks) {
      h8 bh[4], bl[4];
#pragma unroll
      for (int nt = 0; nt < 4; ++nt) {
        int off = (wc * 64 + nt * 16 + l16) * ST + ks * 32 + quad * 8;
        bh[nt] = *(const h8*)&Bh[off];
        bl[nt] = *(const h8*)&Bl[off];
      }
#pragma unroll
      for (int mt = 0; mt < 4; ++mt) {
        int off = (wr * 64 + mt * 16 + l16) * ST + ks * 32 + quad * 8;
        h8 ah = *(const h8*)&Ah[off];
        h8 al = *(const h8*)&Al[off];
#pragma unroll
        for (int nt = 0; nt < 4; ++nt) {
          acc[mt][nt] = __builtin_amdgcn_mfma_f32_16x16x32_f16(ah, bh[nt], acc[mt][nt], 0, 0, 0);
          acc[mt][nt] = __builtin_amdgcn_mfma_f32_16x16x32_f16(ah, bl[nt], acc[mt][nt], 0, 0, 0);
          acc[mt][nt] = __builtin_amdgcn_mfma_f32_16x16x32_f16(al, bh[nt], acc[mt][nt], 0, 0, 0);
        }
      }
    }
  }

  // epilogue: LDS transpose -> coalesced float4 stores with xx correction
  __syncthreads();
  float* S = (float*)sm;               // 128 x 132
#pragma unroll
  for (int mt = 0; mt < 4; ++mt)
#pragma unroll
    for (int nt = 0; nt < 4; ++nt)
#pragma unroll
      for (int i = 0; i < 4; ++i) {
        int rm = wr * 64 + mt * 16 + quad * 4 + i;
        int cn = wc * 64 + nt * 16 + l16;
        S[rm * 132 + cn] = 2.f * acc[mt][nt][i];
      }
  __syncthreads();
  const float* xxb = xx + b * N_PTS;
  float* Db = D + (size_t)b_local * N_PTS * N_PTS;
#pragma unroll
  for (int j = 0; j < 16; ++j) {
    int flat = j * 256 + tid;          // float4 index 0..4095
    int r = flat >> 5, c4 = (flat & 31) * 4;
    float xr = xxb[row0 + r];
    float4 v = *(const float4*)&S[r * 132 + c4];
    float4 xc4 = *(const float4*)&xxb[col0 + c4];
    float4 o = {v.x - xr - xc4.x, v.y - xr - xc4.y,
                v.z - xr - xc4.z, v.w - xr - xc4.w};
    *(float4*)&Db[(size_t)(row0 + r) * N_PTS + col0 + c4] = o;
  }
}

// ---------------------------------------------------------------- MFMA uv GEMM (split f16)
template<int K>
__global__ __launch_bounds__(256, 2)
void uv_mfma_kernel(const _Float16* __restrict__ Xh,
                    const _Float16* __restrict__ Xl,
                    const _Float16* __restrict__ Wph,
                    const _Float16* __restrict__ Wpl,
                    float* __restrict__ out, int NCOLS) {
  constexpr int ST = 72;
  __shared__ __align__(16) _Float16 sm[4 * 128 * ST];
  _Float16* Ah = sm;
  _Float16* Al = sm + 128 * ST;
  _Float16* Bh = sm + 2 * 128 * ST;
  _Float16* Bl = sm + 3 * 128 * ST;

  int nblk = blockIdx.x >> 7, mblk = blockIdx.x & 127;
  int row0 = mblk * 128, col0 = nblk * 128;
  int tid = threadIdx.x;
  int wave = tid >> 6, lane = tid & 63;
  int wr = wave >> 1, wc = wave & 1;
  int quad = lane >> 4, l16 = lane & 15;

  f32x4 acc[4][4] = {};

  for (int k0 = 0; k0 < K; k0 += 64) {
    __syncthreads();
#pragma unroll
    for (int i = 0; i < 4; ++i) {
      int idx4 = tid + i * 256;
      int r = idx4 >> 3, c8 = idx4 & 7;
      int ko = k0 + c8 * 8;
      *(float4*)&Ah[r * ST + c8 * 8] = *(const float4*)&Xh[(size_t)(row0 + r) * K + ko];
      *(float4*)&Al[r * ST + c8 * 8] = *(const float4*)&Xl[(size_t)(row0 + r) * K + ko];
      *(float4*)&Bh[r * ST + c8 * 8] = *(const float4*)&Wph[(size_t)(col0 + r) * K + ko];
      *(float4*)&Bl[r * ST + c8 * 8] = *(const float4*)&Wpl[(size_t)(col0 + r) * K + ko];
    }
    __syncthreads();
#pragma unroll
    for (int ks = 0; ks < 2; ++ks) {
      h8 bh[4], bl[4];
#pragma unroll
      for (int nt = 0; nt < 4; ++nt) {
        int off = (wc * 64 + nt * 16 + l16) * ST + ks * 32 + quad * 8;
        bh[nt] = *(const h8*)&Bh[off];
        bl[nt] = *(const h8*)&Bl[off];
      }
#pragma unroll
      for (int mt = 0; mt < 4; ++mt) {
        int off = (wr * 64 + mt * 16 + l16) * ST + ks * 32 + quad * 8;
        h8 ah = *(const h8*)&Ah[off];
        h8 al = *(const h8*)&Al[off];
#pragma unroll
        for (int nt = 0; nt < 4; ++nt) {
          acc[mt][nt] = __builtin_amdgcn_mfma_f32_16x16x32_f16(ah, bh[nt], acc[mt][nt], 0, 0, 0);
          acc[mt][nt] = __builtin_amdgcn_mfma_f32_16x16x32_f16(ah, bl[nt], acc[mt][nt], 0, 0, 0);
          acc[mt][nt] = __builtin_amdgcn_mfma_f32_16x16x32_f16(al, bh[nt], acc[mt][nt], 0, 0, 0);
        }
      }
    }
  }

  __syncthreads();
  float* S = (float*)sm;
#pragma unroll
  for (int mt = 0; mt < 4; ++mt)
#pragma unroll
    for (int nt = 0; nt < 4; ++nt)
#pragma unroll
      for (int i = 0; i < 4; ++i) {
        int rm = wr * 64 + mt * 16 + quad * 4 + i;
        int cn = wc * 64 + nt * 16 + l16;
        S[rm * 132 + cn] = acc[mt][nt][i];
      }
  __syncthreads();
#pragma unroll
  for (int j = 0; j < 16; ++j) {
    int flat = j * 256 + tid;
    int r = flat >> 5, c4 = (flat & 31) * 4;
    float4 v = *(const float4*)&S[r * 132 + c4];
    *(float4*)&out[(size_t)(row0 + r) * NCOLS + col0 + c4] = v;
  }
}

// ---------------------------------------------------------------- MFMA W5 GEMM + bn/lrelu + pooling
__global__ __launch_bounds__(256, 2)
void w5_mfma_kernel(const _Float16* __restrict__ xch,
                    const _Float16* __restrict__ w5h,
                    const float* __restrict__ g5,
                    const float* __restrict__ b5,
                    float* __restrict__ pmax, float* __restrict__ psum) {
  constexpr int ST = 72;
  __shared__ __align__(16) _Float16 sm[2 * 128 * ST];
  __shared__ float redm[2][128], reds[2][128];
  _Float16* Ah = sm;
  _Float16* Bh = sm + 128 * ST;

  int mblk = blockIdx.x >> 3, nblk = blockIdx.x & 7;
  int row0 = mblk * 128, o0 = nblk * 128;
  int tid = threadIdx.x;
  int wave = tid >> 6, lane = tid & 63;
  int wr = wave >> 1, wc = wave & 1;
  int quad = lane >> 4, l16 = lane & 15;

  f32x4 acc[4][4] = {};

  for (int k0 = 0; k0 < XC_CH; k0 += 64) {
    __syncthreads();
#pragma unroll
    for (int i = 0; i < 4; ++i) {       // 1024 (r,c8) pairs
      int idx4 = tid + i * 256;
      int r = idx4 >> 3, c8 = idx4 & 7;
      int ko = k0 + c8 * 8;
      *(float4*)&Ah[r * ST + c8 * 8] = *(const float4*)&xch[(size_t)(row0 + r) * XC_CH + ko];
      *(float4*)&Bh[r * ST + c8 * 8] = *(const float4*)&w5h[(size_t)(o0 + r) * XC_CH + ko];
    }
    __syncthreads();
#pragma unroll
    for (int ks = 0; ks < 2; ++ks) {
      h8 bh[4];
#pragma unroll
      for (int nt = 0; nt < 4; ++nt)
        bh[nt] = *(const h8*)&Bh[(wc * 64 + nt * 16 + l16) * ST + ks * 32 + quad * 8];
#pragma unroll
      for (int mt = 0; mt < 4; ++mt) {
        h8 ah = *(const h8*)&Ah[(wr * 64 + mt * 16 + l16) * ST + ks * 32 + quad * 8];
#pragma unroll
        for (int nt = 0; nt < 4; ++nt)
          acc[mt][nt] = __builtin_amdgcn_mfma_f32_16x16x32_f16(ah, bh[nt], acc[mt][nt], 0, 0, 0);
      }
    }
  }

#pragma unroll
  for (int nt = 0; nt < 4; ++nt) {
    int gcol = o0 + wc * 64 + nt * 16 + l16;
    float g = g5[gcol], be = b5[gcol];
    float pm = -FLT_MAX, ps = 0.f;
#pragma unroll
    for (int mt = 0; mt < 4; ++mt)
#pragma unroll
      for (int i = 0; i < 4; ++i) {
        float y = g * (acc[mt][nt][i] * BN_SCALE_F) + be;
        y = (y > 0.f) ? y : 0.2f * y;
        pm = fmaxf(pm, y);
        ps += y;
      }
#pragma unroll
    for (int off = 16; off <= 32; off <<= 1) {
      pm = fmaxf(pm, __shfl_xor(pm, off));
      ps += __shfl_xor(ps, off);
    }
    if (quad == 0) {
      redm[wr][wc * 64 + nt * 16 + l16] = pm;
      reds[wr][wc * 64 + nt * 16 + l16] = ps;
    }
  }
  __syncthreads();
  if (tid < 128) {
    float m = fmaxf(redm[0][tid], redm[1][tid]);
    float s = reds[0][tid] + reds[1][tid];
    int bb = mblk >> 4, ch = mblk & 15;
    size_t off = (size_t)(bb * 16 + ch) * 1024 + o0 + tid;
    pmax[off] = m;
    psum[off] = s;
  }
}

// ---------------------------------------------------------------- W' prep (layer1, fp32)
__global__ void prep_wp3_kernel(const float* __restrict__ W,
                                float* __restrict__ Wp, int O, int C) {
  int t = blockIdx.x * 256 + threadIdx.x;
  if (t >= 2 * O * C) return;
  int o = t / C, c = t % C;
  Wp[t] = (o < O) ? W[(size_t)o * 2 * C + c]
                  : (W[(size_t)(o - O) * 2 * C + C + c] -
                     W[(size_t)(o - O) * 2 * C + c]);
}

// ---------------------------------------------------------------- W' prep (f16 hi/lo)
__global__ void prep_wpf16_kernel(const float* __restrict__ W,
                                  _Float16* __restrict__ Wph,
                                  _Float16* __restrict__ Wpl, int O, int C) {
  int t = blockIdx.x * 256 + threadIdx.x;
  if (t >= 2 * O * C) return;
  int o = t / C, c = t % C;
  float val = (o < O) ? W[(size_t)o * 2 * C + c]
                      : (W[(size_t)(o - O) * 2 * C + C + c] -
                         W[(size_t)(o - O) * 2 * C + c]);
  _Float16 hv = (_Float16)val;
  Wph[t] = hv;
  Wpl[t] = (_Float16)(val - (float)hv);
}

// ---------------------------------------------------------------- layer-1 uv (K=3, fp32)
__global__ void gemm_uv3_kernel(const float* __restrict__ x,
                                const float* __restrict__ Wp,
                                float* __restrict__ out) {
  int t = blockIdx.x * 256 + threadIdx.x;
  if (t >= BATCH * N_PTS * 128) return;
  int n = t >> 7, o = t & 127;
  const float* xr = x + (size_t)n * 3;
  const float* wr = Wp + (size_t)o * 3;
  out[t] = xr[0] * wr[0] + xr[1] * wr[1] + xr[2] * wr[2];
}

// ---------------------------------------------------------------- edge gather+max, fused next-layer prep
// Writes: xch slice (f16, stride XC_CH) always; if WS also the packed hi/lo
// split (Xh/Xl, stride O) and xx[n] = sum_o mx^2 (replaces split_sq_kernel).
template<int O, bool WS>
__global__ void edge_max_kernel(const float* __restrict__ uv,
                                const int* __restrict__ knn_idx,
                                const float* __restrict__ gamma,
                                const float* __restrict__ beta,
                                _Float16* __restrict__ xch_out,
                                _Float16* __restrict__ Xh,
                                _Float16* __restrict__ Xl,
                                float* __restrict__ xx) {
  constexpr int P = 256 / O;
  int tid = threadIdx.x;
  int p = tid / O, o = tid % O;
  int n = blockIdx.x * P + p;
  int b = n / N_PTS;
  float v = uv[(size_t)n * (2 * O) + O + o];
  float g = gamma[o], be = beta[o];
  const int* ir = knn_idx + (size_t)n * KNN_K;
  int mk[KNN_K];
#pragma unroll
  for (int k = 0; k < KNN_K; ++k) mk[k] = ir[k];
  float mx = -FLT_MAX;
#pragma unroll
  for (int k = 0; k < KNN_K; ++k) {
    float u = uv[(size_t)(b * N_PTS + mk[k]) * (2 * O) + o];
    float y = g * ((u + v) * BN_SCALE_F) + be;
    y = (y > 0.f) ? y : 0.2f * y;
    mx = fmaxf(mx, y);
  }
  xch_out[(size_t)n * XC_CH + o] = (_Float16)mx;
  if constexpr (WS) {
    _Float16 hv = (_Float16)mx;
    Xh[(size_t)n * O + o] = hv;
    Xl[(size_t)n * O + o] = (_Float16)(mx - (float)hv);
    float sq = mx * mx;
    if constexpr (O == 64) {
#pragma unroll
      for (int off = 32; off > 0; off >>= 1) sq += __shfl_xor(sq, off);
      if ((tid & 63) == 0) xx[n] = sq;
    } else {  // O == 128: two waves per row
      __shared__ float sred[4];
#pragma unroll
      for (int off = 32; off > 0; off >>= 1) sq += __shfl_xor(sq, off);
      if ((tid & 63) == 0) sred[tid >> 6] = sq;
      __syncthreads();
      if (tid < P) xx[blockIdx.x * P + tid] = sred[tid * 2] + sred[tid * 2 + 1];
    }
  }
}

// ---------------------------------------------------------------- head
__global__ void pool_kernel(const float* __restrict__ pmax,
                            const float* __restrict__ psum,
                            float* __restrict__ gvec) {
  int t = blockIdx.x * 256 + threadIdx.x;   // 8192 threads
  int b = t >> 10, o = t & 1023;
  float mx = -FLT_MAX, sm = 0.f;
#pragma unroll
  for (int ch = 0; ch < 16; ++ch) {
    size_t idx = (size_t)(b * 16 + ch) * 1024 + o;
    mx = fmaxf(mx, pmax[idx]);
    sm += psum[idx];
  }
  gvec[b * 2048 + o] = mx;
  gvec[b * 2048 + 1024 + o] = sm * (1.f / 2048.f);
}

__global__ void fc1_kernel(const float* __restrict__ gvec,
                           const float* __restrict__ L1,
                           const float* __restrict__ g6, const float* __restrict__ b6,
                           float* __restrict__ h1) {
  int o = blockIdx.x * 4 + (threadIdx.x >> 6);   // 0..511
  int lane = threadIdx.x & 63;
  float4 w[8];
#pragma unroll
  for (int i = 0; i < 8; ++i)
    w[i] = *(const float4*)&L1[(size_t)o * 2048 + i * 256 + lane * 4];
  float g = g6[o], be = b6[o];
  for (int b = 0; b < BATCH; ++b) {
    float s = 0.f;
#pragma unroll
    for (int i = 0; i < 8; ++i) {
      float4 v = *(const float4*)&gvec[b * 2048 + i * 256 + lane * 4];
      s += w[i].x * v.x + w[i].y * v.y + w[i].z * v.z + w[i].w * v.w;
    }
#pragma unroll
    for (int off = 32; off > 0; off >>= 1) s += __shfl_down(s, off);
    if (lane == 0) {
      float y = g * (s * BN_SCALE_F) + be;
      h1[b * 512 + o] = (y > 0.f) ? y : 0.2f * y;
    }
  }
}

__global__ void fc2_kernel(const float* __restrict__ h1,
                           const float* __restrict__ L2, const float* __restrict__ L2b,
                           const float* __restrict__ g7, const float* __restrict__ b7,
                           float* __restrict__ h2) {
  int w = blockIdx.x * 4 + (threadIdx.x >> 6);   // 0..2047
  int lane = threadIdx.x & 63;
  int b = w >> 8, o = w & 255;
  float s = 0.f;
#pragma unroll
  for (int i = 0; i < 2; ++i) {
    float4 wv = *(const float4*)&L2[(size_t)o * 512 + i * 256 + lane * 4];
    float4 hv = *(const float4*)&h1[b * 512 + i * 256 + lane * 4];
    s += wv.x * hv.x + wv.y * hv.y + wv.z * hv.z + wv.w * hv.w;
  }
#pragma unroll
  for (int off = 32; off > 0; off >>= 1) s += __shfl_down(s, off);
  if (lane == 0) {
    float y = g7[o] * ((s + L2b[o]) * BN_SCALE_F) + b7[o];
    h2[b * 256 + o] = (y > 0.f) ? y : 0.2f * y;
  }
}

__global__ void fc3_kernel(const float* __restrict__ h2,
                           const float* __restrict__ L3, const float* __restrict__ L3b,
                           float* __restrict__ out) {
  int w = blockIdx.x * 4 + (threadIdx.x >> 6);   // 0..79
  int lane = threadIdx.x & 63;
  int b = w / 10, o = w - b * 10;
  float4 wv = *(const float4*)&L3[(size_t)o * 256 + lane * 4];
  float4 hv = *(const float4*)&h2[b * 256 + lane * 4];
  float s = wv.x * hv.x + wv.y * hv.y + wv.z * hv.z + wv.w * hv.w;
#pragma unroll
  for (int off = 32; off > 0; off >>= 1) s += __shfl_down(s, off);
  if (lane == 0) out[b * 10 + o] = s + L3b[o];
}

// ---------------------------------------------------------------- launch
extern "C" void kernel_launch(void* const* d_in, const int* in_sizes, int n_in,
                              void* d_out, int out_size, void* d_ws, size_t ws_size,
                              hipStream_t stream) {
  const float* x   = (const float*)d_in[0];
  const float* W1  = (const float*)d_in[1];
  const float* g1  = (const float*)d_in[2];
  const float* b1  = (const float*)d_in[3];
  const float* W2  = (const float*)d_in[4];
  const float* g2  = (const float*)d_in[5];
  const float* b2  = (const float*)d_in[6];
  const float* W3  = (const float*)d_in[7];
  const float* g3  = (const float*)d_in[8];
  const float* b3  = (const float*)d_in[9];
  const float* W4  = (const float*)d_in[10];
  const float* g4  = (const float*)d_in[11];
  const float* b4  = (const float*)d_in[12];
  const float* W5  = (const float*)d_in[13];
  const float* g5  = (const float*)d_in[14];
  const float* b5  = (const float*)d_in[15];
  const float* L1  = (const float*)d_in[16];
  const float* g6  = (const float*)d_in[17];
  const float* b6  = (const float*)d_in[18];
  const float* L2  = (const float*)d_in[19];
  const float* L2b = (const float*)d_in[20];
  const float* g7  = (const float*)d_in[21];
  const float* b7  = (const float*)d_in[22];
  const float* L3  = (const float*)d_in[23];
  const float* L3b = (const float*)d_in[24];
  float* out = (float*)d_out;

  // ---- workspace layout (bytes) — no fp32 xc
  char* p = (char*)d_ws;
  float* xx = (float*)p;          p += 16384 * 4;
  int*   idx = (int*)p;           p += (size_t)16384 * KNN_K * 4; // 1.31 MB
  float* wp = (float*)p;          p += 2 * 64 * 3 * 4 + 64;       // layer1 fp32 W'
  _Float16* wph = (_Float16*)p;   p += (size_t)512 * 128 * 2;
  _Float16* wpl = (_Float16*)p;   p += (size_t)512 * 128 * 2;
  _Float16* Xh = (_Float16*)p;    p += (size_t)16384 * 128 * 2;   // 4.19 MB
  _Float16* Xl = (_Float16*)p;    p += (size_t)16384 * 128 * 2;
  _Float16* xch = (_Float16*)p;   p += (size_t)16384 * 512 * 2;   // 16.78 MB dedicated
  float* gvec = (float*)p;        p += BATCH * 2048 * 4;          // 64 KB
  float* h1g  = (float*)p;        p += BATCH * 512 * 4;
  float* h2g  = (float*)p;        p += BATCH * 256 * 4;
  char* region = p;
  size_t baseB = (size_t)(region - (char*)d_ws);

  // region users: D (NB*16.78MB) | uv (33.55MB) | w5h+pools (~1.2MB)
  // NB up-to-8 (r12/r14 proven): r13's NB=2 cap regressed (launch
  // serialization), r8's in-kernel fusion regressed (panel spill).
  const size_t dB1 = (size_t)N_PTS * N_PTS * 4;
  const size_t uvB = (size_t)16384 * 512 * 4;
  int NB = 1;
  for (int cand = 8; cand >= 1; cand >>= 1) {
    size_t need = (size_t)cand * dB1 > uvB ? (size_t)cand * dB1 : uvB;
    if (baseB + need <= ws_size) { NB = cand; break; }
  }

  float* D  = (float*)region;
  float* uv = (float*)region;
  _Float16* w5h = (_Float16*)region;                 // after uv dead
  float* pmax = (float*)(w5h + (size_t)1024 * 512);
  float* psum = pmax + (size_t)BATCH * 16 * 1024;

  const int NPTS_TOT = BATCH * N_PTS;            // 16384

  // ================= layer 1: x (C=3) -> xch[:,0:64] + Xh/Xl/xx (no D, sqnorm fused)
  topk3_kernel<<<BATCH * 256, 512, 0, stream>>>(x, idx);
  prep_wp3_kernel<<<2, 256, 0, stream>>>(W1, wp, 64, 3);
  gemm_uv3_kernel<<<(NPTS_TOT * 128 + 255) / 256, 256, 0, stream>>>(x, wp, uv);
  edge_max_kernel<64, true><<<NPTS_TOT / 4, 256, 0, stream>>>(
      uv, idx, g1, b1, xch + 0, Xh, Xl, xx);

  // ================= layer 2: x1 (C=64) -> xch[:,64:128] + Xh/Xl/xx
  for (int b0 = 0; b0 < BATCH; b0 += NB) {
    dist_mfma_kernel<64><<<NB * 256, 256, 0, stream>>>(Xh, Xl, xx, b0, D);
    topk_kernel<<<NB * N_PTS / 4, 256, 0, stream>>>(D, b0, idx);
  }
  prep_wpf16_kernel<<<(2 * 64 * 64 + 255) / 256, 256, 0, stream>>>(W2, wph, wpl, 64, 64);
  uv_mfma_kernel<64><<<1 * 128, 256, 0, stream>>>(Xh, Xl, wph, wpl, uv, 128);
  edge_max_kernel<64, true><<<NPTS_TOT / 4, 256, 0, stream>>>(
      uv, idx, g2, b2, xch + 64, Xh, Xl, xx);

  // ================= layer 3: x2 (C=64) -> xch[:,128:256] + Xh/Xl/xx (128-wide)
  for (int b0 = 0; b0 < BATCH; b0 += NB) {
    dist_mfma_kernel<64><<<NB * 256, 256, 0, stream>>>(Xh, Xl, xx, b0, D);
    topk_kernel<<<NB * N_PTS / 4, 256, 0, stream>>>(D, b0, idx);
  }
  prep_wpf16_kernel<<<(2 * 128 * 64 + 255) / 256, 256, 0, stream>>>(W3, wph, wpl, 128, 64);
  uv_mfma_kernel<64><<<2 * 128, 256, 0, stream>>>(Xh, Xl, wph, wpl, uv, 256);
  edge_max_kernel<128, true><<<NPTS_TOT / 2, 256, 0, stream>>>(
      uv, idx, g3, b3, xch + 128, Xh, Xl, xx);

  // ================= layer 4: x3 (C=128) -> xch[:,256:512] only
  for (int b0 = 0; b0 < BATCH; b0 += NB) {
    dist_mfma_kernel<128><<<NB * 256, 256, 0, stream>>>(Xh, Xl, xx, b0, D);
    topk_kernel<<<NB * N_PTS / 4, 256, 0, stream>>>(D, b0, idx);
  }
  prep_wpf16_kernel<<<(2 * 256 * 128 + 255) / 256, 256, 0, stream>>>(W4, wph, wpl, 256, 128);
  uv_mfma_kernel<128><<<4 * 128, 256, 0, stream>>>(Xh, Xl, wph, wpl, uv, 512);
  edge_max_kernel<256, false><<<NPTS_TOT, 256, 0, stream>>>(
      uv, idx, g4, b4, xch + 256, nullptr, nullptr, nullptr);

  // ================= W5 (f16 MFMA) + pooling, GEMV head
  cvt_f16_kernel<<<(1024 * 512 / 4 + 255) / 256, 256, 0, stream>>>(W5, w5h, 1024 * 512 / 4);
  w5_mfma_kernel<<<128 * 8, 256, 0, stream>>>(xch, w5h, g5, b5, pmax, psum);
  pool_kernel<<<32, 256, 0, stream>>>(pmax, psum, gvec);
  fc1_kernel<<<128, 256, 0, stream>>>(gvec, L1, g6, b6, h1g);
  fc2_kernel<<<512, 256, 0, stream>>>(h1g, L2, L2b, g7, b7, h2g);
  fc3_kernel<<<20, 256, 0, stream>>>(h2g, L3, L3b, out);
}